// Round 4
// baseline (308.992 us; speedup 1.0000x reference)
//
#include <hip/hip_runtime.h>
#include <hip/hip_bf16.h>
#include <cstdint>
#include <cstddef>

#define N_NODES 50000
#define N_EDGES 800000
#define IN_CH 64
#define HID_CH 128
#define N_GRAPHS 64

#define NB_SCAN ((N_NODES + 255) / 256)          // 196
#define NB_CNT4 ((N_EDGES + 1023) / 1024)        // 782 (4 edges/thread)
#define ROWG 4                                    // row-groups (64 rows) per gemm block
#define NB_GRP ((N_NODES + 64 * ROWG - 1) / (64 * ROWG))  // 196
#define NB_GEMM_L (NB_GRP * 4)                   // 784 (one mat per block, ROWG groups)
#define W_ELEMS (4 * IN_CH * 128 + 4 * HID_CH * 128)  // 98304
#define NB_CONV ((W_ELEMS + 255) / 256)          // 384

typedef short s16x8 __attribute__((ext_vector_type(8)));
typedef float f32x4 __attribute__((ext_vector_type(4)));
typedef float f32x2 __attribute__((ext_vector_type(2)));

__device__ __forceinline__ float bf2f(__hip_bfloat16 v) { return __bfloat162float(v); }
__device__ __forceinline__ float bfbits2f(unsigned hs) {
  union { unsigned u; float f; } v; v.u = hs << 16; return v.f;
}
__device__ __forceinline__ float bfhi2f(unsigned w) {
  union { unsigned u; float f; } v; v.u = w & 0xffff0000u; return v.f;
}
__device__ __forceinline__ short f2bfs(float f) {
  __hip_bfloat16 h = __float2bfloat16(f); return *(short*)&h;
}
__device__ __forceinline__ unsigned short f2bfu(float f) {
  __hip_bfloat16 h = __float2bfloat16(f); return *(unsigned short*)&h;
}
__device__ __forceinline__ int clamp_id(int v) {
  if (v < 0) v = 0;
  if (v >= N_NODES) v = N_NODES - 1;
  return v;
}

// fp8 e4m3 (OCP) pack/unpack via gfx950 HW converters (word-selects are immediates).
__device__ __forceinline__ unsigned char f2fp8(float v) {
  return (unsigned char)(__builtin_amdgcn_cvt_pk_fp8_f32(v, v, 0, false) & 0xff);
}
template<bool HI>
__device__ __forceinline__ f32x2 fp8pair(unsigned w) {
  return __builtin_amdgcn_cvt_pk_f32_fp8(w, HI);
}

// ---------------- A: degree-count(+rank) + weight canonicalization ----------------
// cnt zeroing via hipMemsetAsync (stream-ordered before this kernel). The atomicAdd
// return value IS the edge's intra-segment rank -> saved so the scatter needs no
// second atomic round (R1-verified).
__global__ __launch_bounds__(256)
void prep(const int* __restrict__ ei, int* __restrict__ cnt,
          unsigned short* __restrict__ rank,
          const float* __restrict__ w1q, const float* __restrict__ w1k,
          const float* __restrict__ w1v, const float* __restrict__ w1s,
          const float* __restrict__ w2q, const float* __restrict__ w2k,
          const float* __restrict__ w2v, const float* __restrict__ w2s,
          __hip_bfloat16* d1q, __hip_bfloat16* d1k, __hip_bfloat16* d1v, __hip_bfloat16* d1s,
          __hip_bfloat16* d2q, __hip_bfloat16* d2k, __hip_bfloat16* d2v, __hip_bfloat16* d2s)
{
  int bx = blockIdx.x;
  if (bx < NB_CNT4) {
    int e0 = bx * 1024 + threadIdx.x * 4;
    if (e0 >= N_EDGES) return;
    if (e0 + 3 < N_EDGES) {
      int4 dv = *(const int4*)(ei + N_EDGES + e0);
      unsigned short r0 = (unsigned short)atomicAdd(&cnt[clamp_id(dv.x)], 1);
      unsigned short r1 = (unsigned short)atomicAdd(&cnt[clamp_id(dv.y)], 1);
      unsigned short r2 = (unsigned short)atomicAdd(&cnt[clamp_id(dv.z)], 1);
      unsigned short r3 = (unsigned short)atomicAdd(&cnt[clamp_id(dv.w)], 1);
      ushort4 rv; rv.x = r0; rv.y = r1; rv.z = r2; rv.w = r3;
      *(ushort4*)(rank + e0) = rv;
    } else {
      for (int j = 0; j < 4; ++j)
        if (e0 + j < N_EDGES)
          rank[e0 + j] = (unsigned short)atomicAdd(&cnt[clamp_id(ei[N_EDGES + e0 + j])], 1);
    }
    return;
  }
  int j = (bx - NB_CNT4) * 256 + threadIdx.x;
  if (j >= W_ELEMS) return;
  const float* S[8] = {w1q, w1k, w1v, w1s, w2q, w2k, w2v, w2s};
  __hip_bfloat16* D[8] = {d1q, d1k, d1v, d1s, d2q, d2k, d2v, d2s};
  int m, r;
  if (j < 4 * IN_CH * 128) { m = j >> 13; r = j & 8191; }
  else { int jj = j - 4 * IN_CH * 128; m = 4 + (jj >> 14); r = jj & 16383; }
  int k = r >> 7, c = r & 127;
  D[m][(((k >> 3) * 128 + c) << 3) + (k & 7)] = __float2bfloat16(S[m][r]);
}

// ---------------- gemm body: one mat per block, ROWG row-groups, pipelined ----------------
// R4: weights staged ONCE per block (R3's per-group restage was pure overhead: FETCH
// 11->30 MB, no speedup), then a barrier-free loop over ROWG 64-row groups with a
// 1-deep A-fragment register prefetch, so the global-load latency of group g+1 hides
// under MFMA+stores of group g. R0-R3 showed this kernel is latency-bound (all pipes
// <12%, occupancy ~36% regardless of grid size) -> attack the serial chain itself.
// X must NOT alias any output (4 mat-blocks read the same X rows).
// mat: 0=Q (bf16, row 128), 1=K -> KV8 byte [0..128), 2=V -> KV8 [128..256), 3=S.
template<int KD, int XF32>
__device__ __forceinline__ void gemm_body_loop(
    int grp, int mat, const void* X,
    const short* __restrict__ WT, const float* __restrict__ bias,
    short* Qo, unsigned char* KV8, short* So, short* lds)
{
  constexpr int KT = KD / 32;
  constexpr int CHUNKS = KD * 16;          // uint4 count of a KDx128 bf16 weight image
  const int tid  = threadIdx.x;
  const int wid  = tid >> 6;
  const int lane = tid & 63;
  const int quad = lane >> 4;
  const int mm   = lane & 15;
  const int rt   = wid & 1;
  const int ch   = wid >> 1;

  // stage this mat's weights once
  {
    const uint4* src = (const uint4*)WT;
    uint4* dst = (uint4*)lds;
    #pragma unroll
    for (int i = 0; i < CHUNKS / 256; ++i)
      dst[tid + i * 256] = src[tid + i * 256];
  }

  float bv[4];
  #pragma unroll
  for (int c4 = 0; c4 < 4; ++c4) bv[c4] = bias[ch * 64 + c4 * 16 + mm];

  auto loadA = [&](int bg, s16x8 fr[2][KT]) {
    const int rowbase = bg * 64 + rt * 32;
    #pragma unroll
    for (int t = 0; t < 2; ++t) {
      const int arow = rowbase + t * 16 + mm;
      if (arow < N_NODES) {
        if (XF32) {
          const float* xp = (const float*)X + (size_t)arow * KD;
          #pragma unroll
          for (int kt = 0; kt < KT; ++kt) {
            const float4* p = (const float4*)(xp + kt * 32 + quad * 8);
            float4 a = p[0], b = p[1];
            s16x8 f;
            f[0] = f2bfs(a.x); f[1] = f2bfs(a.y); f[2] = f2bfs(a.z); f[3] = f2bfs(a.w);
            f[4] = f2bfs(b.x); f[5] = f2bfs(b.y); f[6] = f2bfs(b.z); f[7] = f2bfs(b.w);
            fr[t][kt] = f;
          }
        } else {
          const short* xp = (const short*)X + (size_t)arow * KD;
          #pragma unroll
          for (int kt = 0; kt < KT; ++kt)
            fr[t][kt] = *(const s16x8*)(xp + kt * 32 + quad * 8);
        }
      } else {
        #pragma unroll
        for (int kt = 0; kt < KT; ++kt)
          fr[t][kt] = (s16x8){0,0,0,0,0,0,0,0};
      }
    }
  };

  __syncthreads();   // weights resident; the ONLY barrier in this block

  const int bg0 = grp * ROWG;
  s16x8 cur[2][KT], nxt[2][KT];
  loadA(bg0, cur);

  #pragma unroll
  for (int g = 0; g < ROWG; ++g) {
    const int bg = bg0 + g;
    const bool act = (bg * 64 < N_NODES);
    if (g + 1 < ROWG) loadA(bg0 + g + 1, nxt);   // prefetch (self-guarded per row)

    if (act) {
      const int rowbase = bg * 64 + rt * 32;
      f32x4 acc[4][2];
      #pragma unroll
      for (int c4 = 0; c4 < 4; ++c4) {
        f32x4 av = {bv[c4], bv[c4], bv[c4], bv[c4]};
        acc[c4][0] = av; acc[c4][1] = av;
      }
      #pragma unroll
      for (int kt = 0; kt < KT; ++kt) {
        #pragma unroll
        for (int c4 = 0; c4 < 4; ++c4) {
          s16x8 bfrag = *(const s16x8*)(lds + ((((kt * 4 + quad) << 7) + ch * 64 + c4 * 16 + mm) << 3));
          acc[c4][0] = __builtin_amdgcn_mfma_f32_16x16x32_bf16(cur[0][kt], bfrag, acc[c4][0], 0, 0, 0);
          acc[c4][1] = __builtin_amdgcn_mfma_f32_16x16x32_bf16(cur[1][kt], bfrag, acc[c4][1], 0, 0, 0);
        }
      }
      if (mat == 1 || mat == 2) {
        unsigned char* O8 = KV8 + ((mat == 1) ? 0 : 128);
        #pragma unroll
        for (int c4 = 0; c4 < 4; ++c4) {
          const int col = ch * 64 + c4 * 16 + mm;
          #pragma unroll
          for (int t = 0; t < 2; ++t) {
            #pragma unroll
            for (int r = 0; r < 4; ++r) {
              int row = rowbase + t * 16 + quad * 4 + r;
              if (row < N_NODES)
                O8[(size_t)row * 256 + col] = f2fp8(acc[c4][t][r]);
            }
          }
        }
      } else {
        short* O = (mat == 0) ? Qo : So;
        #pragma unroll
        for (int c4 = 0; c4 < 4; ++c4) {
          const int col = ch * 64 + c4 * 16 + mm;
          #pragma unroll
          for (int t = 0; t < 2; ++t) {
            #pragma unroll
            for (int r = 0; r < 4; ++r) {
              int row = rowbase + t * 16 + quad * 4 + r;
              if (row < N_NODES)
                ((__hip_bfloat16*)O)[(size_t)row * 128 + col] = __float2bfloat16(acc[c4][t][r]);
            }
          }
        }
      }
    }

    #pragma unroll
    for (int t = 0; t < 2; ++t)
      #pragma unroll
      for (int kt = 0; kt < KT; ++kt)
        cur[t][kt] = nxt[t][kt];   // register rotate (renamed away, fully unrolled)
  }
}

// ---------------- C1/C2: scan ----------------
__global__ __launch_bounds__(256)
void scan1(const int* __restrict__ cnt, int* __restrict__ offs, int* __restrict__ bsum) {
  __shared__ int wsum[4];
  int t = threadIdx.x, lane = t & 63, w = t >> 6;
  int i = blockIdx.x * 256 + t;
  int v = (i < N_NODES) ? cnt[i] : 0;
  int x = v;
  #pragma unroll
  for (int o = 1; o < 64; o <<= 1) { int y = __shfl_up(x, o, 64); if (lane >= o) x += y; }
  if (lane == 63) wsum[w] = x;
  __syncthreads();
  if (t == 0) {
    int run = 0;
    #pragma unroll
    for (int k = 0; k < 4; ++k) { int tv = wsum[k]; wsum[k] = run; run += tv; }
    bsum[blockIdx.x] = run;
  }
  __syncthreads();
  if (i <= N_NODES) offs[i] = wsum[w] + x - v;   // block-local exclusive prefix
}

__global__ __launch_bounds__(256)
void scan2(int* __restrict__ bsum) {
  __shared__ int wsum[4];
  int t = threadIdx.x, lane = t & 63, w = t >> 6;
  int v = (t < NB_SCAN) ? bsum[t] : 0;
  int x = v;
  #pragma unroll
  for (int o = 1; o < 64; o <<= 1) { int y = __shfl_up(x, o, 64); if (lane >= o) x += y; }
  if (lane == 63) wsum[w] = x;
  __syncthreads();
  if (t == 0) {
    int run = 0;
    #pragma unroll
    for (int k = 0; k < 4; ++k) { int tv = wsum[k]; wsum[k] = run; run += tv; }
  }
  __syncthreads();
  if (t < NB_SCAN) bsum[t] = wsum[w] + x - v;    // exclusive prefix of block sums
}

// ---------------- D: edge scatter (FIRST: longest latency chains) + layer-1 gemm ----------------
__global__ __launch_bounds__(256)
void scatter_gemm1(const int* __restrict__ ei, const int* __restrict__ offs,
                   const int* __restrict__ bsum, const unsigned short* __restrict__ rank,
                   int* __restrict__ ssrc,
                   const float* __restrict__ X,
                   const short* __restrict__ w1q, const short* __restrict__ w1k,
                   const short* __restrict__ w1v, const short* __restrict__ w1s,
                   const float* __restrict__ b1q, const float* __restrict__ b1k,
                   const float* __restrict__ b1v, const float* __restrict__ b1s,
                   short* Qb, unsigned char* KV8, short* Sb)
{
  __shared__ short lds[IN_CH * 128];   // 16 KB
  int bx = blockIdx.x;
  if (bx < NB_CNT4) {
    int e0 = bx * 1024 + threadIdx.x * 4;
    if (e0 >= N_EDGES) return;
    if (e0 + 3 < N_EDGES) {
      int4 sv = *(const int4*)(ei + e0);
      int4 dv = *(const int4*)(ei + N_EDGES + e0);
      ushort4 rv = *(const ushort4*)(rank + e0);
      int d0 = clamp_id(dv.x), d1 = clamp_id(dv.y);
      int d2 = clamp_id(dv.z), d3 = clamp_id(dv.w);
      int p0 = offs[d0] + bsum[d0 >> 8] + rv.x;
      int p1 = offs[d1] + bsum[d1 >> 8] + rv.y;
      int p2 = offs[d2] + bsum[d2 >> 8] + rv.z;
      int p3 = offs[d3] + bsum[d3 >> 8] + rv.w;
      ssrc[p0] = clamp_id(sv.x);
      ssrc[p1] = clamp_id(sv.y);
      ssrc[p2] = clamp_id(sv.z);
      ssrc[p3] = clamp_id(sv.w);
    } else {
      for (int j = 0; j < 4; ++j) {
        int e = e0 + j;
        if (e < N_EDGES) {
          int src = clamp_id(ei[e]);
          int dst = clamp_id(ei[N_EDGES + e]);
          ssrc[offs[dst] + bsum[dst >> 8] + rank[e]] = src;
        }
      }
    }
    return;
  }
  const int b   = bx - NB_CNT4;
  const int grp = b >> 2;
  const int mat = b & 3;
  const short* wts[4] = {w1q, w1k, w1v, w1s};
  const float* bias[4] = {b1q, b1k, b1v, b1s};
  gemm_body_loop<IN_CH, 1>(grp, mat, X, wts[mat], bias[mat], Qb, KV8, Sb, lds);
}

// ---------------- attention (fp8 K/V, interleaved 256B rows) ----------------
// 1 wave per dst (4 dsts/block); 4 edge slots x 16 channel-lanes; quad=head.
// No-max softmax in exp2 domain; 1-deep K/V register prefetch.
// H may alias S (in-place per dst row: same wave reads then writes).
__global__ __launch_bounds__(256)
void attn_kernel(const unsigned short* __restrict__ Q, const unsigned char* __restrict__ KV8,
                 const unsigned short* S,
                 const int* __restrict__ offs, const int* __restrict__ bsum,
                 const int* __restrict__ ssrc, unsigned short* H)
{
  const int dst = blockIdx.x * 4 + (threadIdx.x >> 6);
  if (dst >= N_NODES) return;               // wave-uniform
  const int lane = threadIdx.x & 63;
  const int sub  = lane >> 4;
  const int cl   = lane & 15;

  const float qs = 0.17677669529663687f * 1.4426950408889634f;  // 1/sqrt(32)*log2(e)
  uint4 qw = *(const uint4*)(Q + (size_t)dst * 128 + cl * 8);
  float q[8], a[8];
  #pragma unroll
  for (int i = 0; i < 4; ++i) {
    unsigned w = ((unsigned*)&qw)[i];
    q[2 * i]     = bfbits2f(w & 0xffffu) * qs;
    q[2 * i + 1] = bfhi2f(w) * qs;
    a[2 * i] = 0.f; a[2 * i + 1] = 0.f;
  }
  float s = 0.f;

  const int e0 = offs[dst] + bsum[dst >> 8];
  const int e1 = offs[dst + 1] + bsum[(dst + 1) >> 8];
  const int iters = (e1 - e0 + 3) >> 2;

  if (iters > 0) {
    int e = e0 + sub;
    bool have = (e < e1);
    int src = have ? ssrc[e] : ssrc[e0];
    float ph = have ? 1.f : 0.f;
    const unsigned char* kvp = KV8 + (size_t)src * 256 + cl * 8;
    uint2 kw = *(const uint2*)(kvp);
    uint2 vw = *(const uint2*)(kvp + 128);

    for (int it = 0; it < iters; ++it) {
      uint2 kwn, vwn;
      int en = e + 4;
      bool haven = (en < e1);
      float phn = haven ? 1.f : 0.f;
      if (it + 1 < iters) {                 // wave-uniform
        int srcn = haven ? ssrc[en] : ssrc[e0];
        const unsigned char* kvn = KV8 + (size_t)srcn * 256 + cl * 8;
        kwn = *(const uint2*)(kvn);
        vwn = *(const uint2*)(kvn + 128);
      } else {
        kwn = kw; vwn = vw;
      }
      f32x2 k0 = fp8pair<false>(kw.x), k1 = fp8pair<true>(kw.x);
      f32x2 k2 = fp8pair<false>(kw.y), k3 = fp8pair<true>(kw.y);
      float d = q[0] * k0.x + q[1] * k0.y + q[2] * k1.x + q[3] * k1.y
              + q[4] * k2.x + q[5] * k2.y + q[6] * k3.x + q[7] * k3.y;
      d += __shfl_xor(d, 1, 64);
      d += __shfl_xor(d, 2, 64);
      float p = exp2f(d) * ph;
      s += p;
      f32x2 v0 = fp8pair<false>(vw.x), v1 = fp8pair<true>(vw.x);
      f32x2 v2 = fp8pair<false>(vw.y), v3 = fp8pair<true>(vw.y);
      a[0] += p * v0.x; a[1] += p * v0.y;
      a[2] += p * v1.x; a[3] += p * v1.y;
      a[4] += p * v2.x; a[5] += p * v2.y;
      a[6] += p * v3.x; a[7] += p * v3.y;
      kw = kwn; vw = vwn; ph = phn; e = en;
    }
  }

  s += __shfl_xor(s, 16, 64);
  s += __shfl_xor(s, 32, 64);
  #pragma unroll
  for (int i = 0; i < 8; ++i) {
    a[i] += __shfl_xor(a[i], 16, 64);
    a[i] += __shfl_xor(a[i], 32, 64);
  }
  const float inv = (s > 0.f) ? (1.0f / s) : 0.f;

  if (sub == 0) {
    uint4 sw = *(const uint4*)(S + (size_t)dst * 128 + cl * 8);
    uint4 ow;
    #pragma unroll
    for (int i = 0; i < 4; ++i) {
      unsigned w = ((unsigned*)&sw)[i];
      float o0 = fmaxf(a[2 * i] * inv     + bfbits2f(w & 0xffffu), 0.f);
      float o1 = fmaxf(a[2 * i + 1] * inv + bfhi2f(w), 0.f);
      ((unsigned*)&ow)[i] = (unsigned)f2bfu(o0) | ((unsigned)f2bfu(o1) << 16);
    }
    *(uint4*)(H + (size_t)dst * 128 + cl * 8) = ow;
  }
}

// ---------------- F: layer-2 gemm (one mat per block, ROWG groups) ----------------
__global__ __launch_bounds__(256)
void gemm2(const short* __restrict__ X,
           const short* __restrict__ w2q, const short* __restrict__ w2k,
           const short* __restrict__ w2v, const short* __restrict__ w2s,
           const float* __restrict__ b2q, const float* __restrict__ b2k,
           const float* __restrict__ b2v, const float* __restrict__ b2s,
           short* Qb, unsigned char* KV8, short* Sb2)
{
  __shared__ short lds[HID_CH * 128];  // 32 KB
  const int grp = blockIdx.x >> 2;
  const int mat = blockIdx.x & 3;
  const short* wts[4] = {w2q, w2k, w2v, w2s};
  const float* bias[4] = {b2q, b2k, b2v, b2s};
  gemm_body_loop<HID_CH, 0>(grp, mat, X, wts[mat], bias[mat], Qb, KV8, Sb2, lds);
}

// ---------------- pooling (16 partials/graph, few atomics) ----------------
__device__ __forceinline__ int lower_bound_i(const int* __restrict__ b, int n, int val) {
  int lo = 0, hi = n;
  while (lo < hi) { int mid = (lo + hi) >> 1; if (b[mid] < val) lo = mid + 1; else hi = mid; }
  return lo;
}

__global__ __launch_bounds__(128)
void pool_partial(const __hip_bfloat16* __restrict__ H, const int* __restrict__ batch,
                  float* __restrict__ pooled)
{
  const int g = blockIdx.x >> 4, p = blockIdx.x & 15, t = threadIdx.x;
  const int s = lower_bound_i(batch, N_NODES, g);
  const int e = lower_bound_i(batch, N_NODES, g + 1);
  const int len = e - s;
  if (len <= 0) return;
  const int chunk = (len + 15) >> 4;
  const int a = s + p * chunk;
  const int b = min(a + chunk, e);
  if (a >= b) return;
  float sum = 0.f;
  for (int i = a; i < b; ++i) sum += bf2f(H[(size_t)i * 128 + t]);
  atomicAdd(&pooled[g * 128 + t], sum);
}

__global__ __launch_bounds__(128)
void pool_final(const float* __restrict__ pooled, const int* __restrict__ batch,
                const float* __restrict__ Wl, const float* __restrict__ bl,
                float* __restrict__ out)
{
  const int g = blockIdx.x, t = threadIdx.x;
  __shared__ float r0[128], r1[128];
  const int s = lower_bound_i(batch, N_NODES, g);
  const int e = lower_bound_i(batch, N_NODES, g + 1);
  const float inv = 1.0f / (float)max(e - s, 1);
  const float pc = pooled[g * 128 + t] * inv;
  r0[t] = pc * Wl[t * 2 + 0];
  r1[t] = pc * Wl[t * 2 + 1];
  __syncthreads();
  for (int o = 64; o > 0; o >>= 1) {
    if (t < o) { r0[t] += r0[t + o]; r1[t] += r1[t + o]; }
    __syncthreads();
  }
  if (t == 0) {
    out[g * 2 + 0] = r0[0] + bl[0];
    out[g * 2 + 1] = r1[0] + bl[1];
  }
}

// ---------------- launch ----------------

extern "C" void kernel_launch(void* const* d_in, const int* in_sizes, int n_in,
                              void* d_out, int out_size, void* d_ws, size_t ws_size,
                              hipStream_t stream) {
  uintptr_t base = (uintptr_t)d_ws;
  auto take = [&](size_t bytes) -> uintptr_t {
    uintptr_t p = base;
    base += (bytes + 255) & ~(size_t)255;
    return p;
  };

  // cnt + pooled first and contiguous: zeroed by ONE hipMemsetAsync.
  int*   cnt    = (int*)take((size_t)N_NODES * 4);
  float* pooled = (float*)take((size_t)N_GRAPHS * 128 * 4);
  int*   offs   = (int*)take((size_t)(N_NODES + 1) * 4);
  int*   bsum   = (int*)take((size_t)NB_SCAN * 4);
  int*   ssrc   = (int*)take((size_t)N_EDGES * 4);
  unsigned short* rank = (unsigned short*)take((size_t)N_EDGES * 2);
  short* Qb     = (short*)take((size_t)N_NODES * 128 * 2);
  unsigned char* KV8 = (unsigned char*)take((size_t)N_NODES * 256);  // fp8 [K|V] rows
  short* Sb     = (short*)take((size_t)N_NODES * 128 * 2);  // layer-1 S -> H1 -> layer-2 X
  short* Sb2    = (short*)take((size_t)N_NODES * 128 * 2);  // layer-2 S -> H2 (no X alias)
  short* wt1q   = (short*)take((size_t)IN_CH * 128 * 2);
  short* wt1k   = (short*)take((size_t)IN_CH * 128 * 2);
  short* wt1v   = (short*)take((size_t)IN_CH * 128 * 2);
  short* wt1s   = (short*)take((size_t)IN_CH * 128 * 2);
  short* wt2q   = (short*)take((size_t)HID_CH * 128 * 2);
  short* wt2k   = (short*)take((size_t)HID_CH * 128 * 2);
  short* wt2v   = (short*)take((size_t)HID_CH * 128 * 2);
  short* wt2s   = (short*)take((size_t)HID_CH * 128 * 2);

  const int* ei    = (const int*)d_in[1];   // int32 per harness contract
  const int* batch = (const int*)d_in[2];   // int32 per harness contract

  // Zero cnt..pooled span (contiguous, one DMA memset; graph-capturable).
  size_t zspan = (size_t)((char*)pooled + (size_t)N_GRAPHS * 128 * 4 - (char*)cnt);
  hipMemsetAsync(cnt, 0, zspan, stream);

  // A: degree count + rank capture (blocks first) + weight canonicalization
  prep<<<NB_CNT4 + NB_CONV, 256, 0, stream>>>(
      ei, cnt, rank,
      (const float*)d_in[3], (const float*)d_in[5], (const float*)d_in[7], (const float*)d_in[9],
      (const float*)d_in[11], (const float*)d_in[13], (const float*)d_in[15], (const float*)d_in[17],
      (__hip_bfloat16*)wt1q, (__hip_bfloat16*)wt1k, (__hip_bfloat16*)wt1v, (__hip_bfloat16*)wt1s,
      (__hip_bfloat16*)wt2q, (__hip_bfloat16*)wt2k, (__hip_bfloat16*)wt2v, (__hip_bfloat16*)wt2s);

  // C: scan
  scan1<<<NB_SCAN, 256, 0, stream>>>(cnt, offs, bsum);
  scan2<<<1, 256, 0, stream>>>(bsum);

  // D: edge scatter (blocks first: longest latency chains) + layer-1 QKVS gemm
  scatter_gemm1<<<NB_CNT4 + NB_GEMM_L, 256, 0, stream>>>(
      ei, offs, bsum, rank, ssrc,
      (const float*)d_in[0],
      wt1q, wt1k, wt1v, wt1s,
      (const float*)d_in[4], (const float*)d_in[6], (const float*)d_in[8], (const float*)d_in[10],
      Qb, KV8, Sb);

  const int attn_grid = (N_NODES + 3) / 4;

  // E: layer-1 attention (writes H in place into Sb)
  attn_kernel<<<attn_grid, 256, 0, stream>>>(
      (const unsigned short*)Qb, KV8,
      (const unsigned short*)Sb, offs, bsum, ssrc, (unsigned short*)Sb);

  // F: layer-2 gemm (X = Sb read-only; S -> Sb2)
  gemm2<<<NB_GEMM_L, 256, 0, stream>>>(
      Sb, wt2q, wt2k, wt2v, wt2s,
      (const float*)d_in[12], (const float*)d_in[14], (const float*)d_in[16], (const float*)d_in[18],
      Qb, KV8, Sb2);

  // G: layer-2 attention (writes H in place into Sb2)
  attn_kernel<<<attn_grid, 256, 0, stream>>>(
      (const unsigned short*)Qb, KV8,
      (const unsigned short*)Sb2, offs, bsum, ssrc, (unsigned short*)Sb2);

  // Pool: 16 partials/graph -> one atomic per channel per partial, then final linear
  pool_partial<<<N_GRAPHS * 16, 128, 0, stream>>>(
      (const __hip_bfloat16*)Sb2, batch, pooled);
  pool_final<<<N_GRAPHS, 128, 0, stream>>>(pooled, batch, (const float*)d_in[19],
                                           (const float*)d_in[20], (float*)d_out);
}

// Round 5
// 299.256 us; speedup vs baseline: 1.0325x; 1.0325x over previous
//
#include <hip/hip_runtime.h>
#include <hip/hip_bf16.h>
#include <cstdint>
#include <cstddef>

#define N_NODES 50000
#define N_EDGES 800000
#define IN_CH 64
#define HID_CH 128
#define N_GRAPHS 64

#define NB_SCAN ((N_NODES + 255) / 256)          // 196
#define NB_CNT4 ((N_EDGES + 1023) / 1024)        // 782 (4 edges/thread)
#define NB_GEMM ((N_NODES + 63) / 64)            // 782
#define W_ELEMS (4 * IN_CH * 128 + 4 * HID_CH * 128)  // 98304
#define NB_CONV ((W_ELEMS + 255) / 256)          // 384

typedef short s16x8 __attribute__((ext_vector_type(8)));
typedef float f32x4 __attribute__((ext_vector_type(4)));
typedef float f32x2 __attribute__((ext_vector_type(2)));

__device__ __forceinline__ float bf2f(__hip_bfloat16 v) { return __bfloat162float(v); }
__device__ __forceinline__ float bfbits2f(unsigned hs) {
  union { unsigned u; float f; } v; v.u = hs << 16; return v.f;
}
__device__ __forceinline__ float bfhi2f(unsigned w) {
  union { unsigned u; float f; } v; v.u = w & 0xffff0000u; return v.f;
}
__device__ __forceinline__ short f2bfs(float f) {
  __hip_bfloat16 h = __float2bfloat16(f); return *(short*)&h;
}
__device__ __forceinline__ unsigned short f2bfu(float f) {
  __hip_bfloat16 h = __float2bfloat16(f); return *(unsigned short*)&h;
}
__device__ __forceinline__ int clamp_id(int v) {
  if (v < 0) v = 0;
  if (v >= N_NODES) v = N_NODES - 1;
  return v;
}

// fp8 e4m3 (OCP) pack/unpack via gfx950 HW converters (word-selects are immediates).
__device__ __forceinline__ unsigned char f2fp8(float v) {
  return (unsigned char)(__builtin_amdgcn_cvt_pk_fp8_f32(v, v, 0, false) & 0xff);
}
template<bool HI>
__device__ __forceinline__ f32x2 fp8pair(unsigned w) {
  return __builtin_amdgcn_cvt_pk_f32_fp8(w, HI);
}

// ---------------- A: degree-count(+rank) + weight canonicalization ----------------
// (R1-verified best structure: cnt zeroed by hipMemsetAsync; atomicAdd return value
// saved as the edge's intra-segment rank so the scatter needs no second atomic.)
__global__ __launch_bounds__(256)
void prep(const int* __restrict__ ei, int* __restrict__ cnt,
          unsigned short* __restrict__ rank,
          const float* __restrict__ w1q, const float* __restrict__ w1k,
          const float* __restrict__ w1v, const float* __restrict__ w1s,
          const float* __restrict__ w2q, const float* __restrict__ w2k,
          const float* __restrict__ w2v, const float* __restrict__ w2s,
          __hip_bfloat16* d1q, __hip_bfloat16* d1k, __hip_bfloat16* d1v, __hip_bfloat16* d1s,
          __hip_bfloat16* d2q, __hip_bfloat16* d2k, __hip_bfloat16* d2v, __hip_bfloat16* d2s)
{
  int bx = blockIdx.x;
  if (bx < NB_CNT4) {
    int e0 = bx * 1024 + threadIdx.x * 4;
    if (e0 >= N_EDGES) return;
    if (e0 + 3 < N_EDGES) {
      int4 dv = *(const int4*)(ei + N_EDGES + e0);
      unsigned short r0 = (unsigned short)atomicAdd(&cnt[clamp_id(dv.x)], 1);
      unsigned short r1 = (unsigned short)atomicAdd(&cnt[clamp_id(dv.y)], 1);
      unsigned short r2 = (unsigned short)atomicAdd(&cnt[clamp_id(dv.z)], 1);
      unsigned short r3 = (unsigned short)atomicAdd(&cnt[clamp_id(dv.w)], 1);
      ushort4 rv; rv.x = r0; rv.y = r1; rv.z = r2; rv.w = r3;
      *(ushort4*)(rank + e0) = rv;
    } else {
      for (int j = 0; j < 4; ++j)
        if (e0 + j < N_EDGES)
          rank[e0 + j] = (unsigned short)atomicAdd(&cnt[clamp_id(ei[N_EDGES + e0 + j])], 1);
    }
    return;
  }
  int j = (bx - NB_CNT4) * 256 + threadIdx.x;
  if (j >= W_ELEMS) return;
  const float* S[8] = {w1q, w1k, w1v, w1s, w2q, w2k, w2v, w2s};
  __hip_bfloat16* D[8] = {d1q, d1k, d1v, d1s, d2q, d2k, d2v, d2s};
  int m, r;
  if (j < 4 * IN_CH * 128) { m = j >> 13; r = j & 8191; }
  else { int jj = j - 4 * IN_CH * 128; m = 4 + (jj >> 14); r = jj & 16383; }
  int k = r >> 7, c = r & 127;
  D[m][(((k >> 3) * 128 + c) << 3) + (k & 7)] = __float2bfloat16(S[m][r]);
}

// ---------------- shared gemm body (R1-verified: 4-mat loop, direct stores) ----------------
// Outputs: mat0=Q (bf16, row 128), mat1=K -> KV8 row byte [0..128), mat2=V -> KV8 [128..256),
// mat3=S (bf16, row 128). KV8 row = 256 bytes, fp8 e4m3.
// So may alias X (in-place per-row: A-frags register-resident before stores).
// R2 (LDS-bounce stores), R3 (per-mat blocks), R4 (ROWG pipeline) all regressed vs this.
template<int KD, int XF32>
__device__ __forceinline__ void gemm_body(
    int bg, const void* X,
    const short* __restrict__ WTq, const short* __restrict__ WTk,
    const short* __restrict__ WTv, const short* __restrict__ WTs,
    const float* __restrict__ bq, const float* __restrict__ bk,
    const float* __restrict__ bv, const float* __restrict__ bs,
    short* Qo, unsigned char* KV8, short* So, short* lds)
{
  constexpr int KT = KD / 32;
  constexpr int CHUNKS = KD * 16;
  const int tid  = threadIdx.x;
  const int wid  = tid >> 6;
  const int lane = tid & 63;
  const int quad = lane >> 4;
  const int mm   = lane & 15;
  const int rt   = wid & 1;
  const int ch   = wid >> 1;
  const int rowbase = bg * 64 + rt * 32;

  s16x8 afrag[2][KT];
  #pragma unroll
  for (int t = 0; t < 2; ++t) {
    const int arow = rowbase + t * 16 + mm;
    if (arow < N_NODES) {
      if (XF32) {
        const float* xp = (const float*)X + (size_t)arow * KD;
        #pragma unroll
        for (int kt = 0; kt < KT; ++kt) {
          const float4* p = (const float4*)(xp + kt * 32 + quad * 8);
          float4 a = p[0], b = p[1];
          s16x8 fr;
          fr[0] = f2bfs(a.x); fr[1] = f2bfs(a.y); fr[2] = f2bfs(a.z); fr[3] = f2bfs(a.w);
          fr[4] = f2bfs(b.x); fr[5] = f2bfs(b.y); fr[6] = f2bfs(b.z); fr[7] = f2bfs(b.w);
          afrag[t][kt] = fr;
        }
      } else {
        const short* xp = (const short*)X + (size_t)arow * KD;
        #pragma unroll
        for (int kt = 0; kt < KT; ++kt)
          afrag[t][kt] = *(const s16x8*)(xp + kt * 32 + quad * 8);
      }
    } else {
      #pragma unroll
      for (int kt = 0; kt < KT; ++kt)
        afrag[t][kt] = (s16x8){0,0,0,0,0,0,0,0};
    }
  }

  const short* wts[4] = {WTq, WTk, WTv, WTs};
  const float* bias[4] = {bq, bk, bv, bs};

  #pragma unroll
  for (int mat = 0; mat < 4; ++mat) {
    if (mat > 0) __syncthreads();
    {
      const uint4* src = (const uint4*)wts[mat];
      uint4* dst = (uint4*)lds;
      #pragma unroll
      for (int i = 0; i < CHUNKS / 256; ++i)
        dst[tid + i * 256] = src[tid + i * 256];
    }
    __syncthreads();

    f32x4 acc[4][2];
    #pragma unroll
    for (int c4 = 0; c4 < 4; ++c4) {
      float b = bias[mat][ch * 64 + c4 * 16 + mm];
      f32x4 av = {b, b, b, b};
      acc[c4][0] = av; acc[c4][1] = av;
    }
    #pragma unroll
    for (int kt = 0; kt < KT; ++kt) {
      #pragma unroll
      for (int c4 = 0; c4 < 4; ++c4) {
        s16x8 bfrag = *(const s16x8*)(lds + ((((kt * 4 + quad) << 7) + ch * 64 + c4 * 16 + mm) << 3));
        acc[c4][0] = __builtin_amdgcn_mfma_f32_16x16x32_bf16(afrag[0][kt], bfrag, acc[c4][0], 0, 0, 0);
        acc[c4][1] = __builtin_amdgcn_mfma_f32_16x16x32_bf16(afrag[1][kt], bfrag, acc[c4][1], 0, 0, 0);
      }
    }
    if (mat == 1 || mat == 2) {
      unsigned char* O8 = KV8 + ((mat == 1) ? 0 : 128);
      #pragma unroll
      for (int c4 = 0; c4 < 4; ++c4) {
        const int col = ch * 64 + c4 * 16 + mm;
        #pragma unroll
        for (int t = 0; t < 2; ++t) {
          #pragma unroll
          for (int r = 0; r < 4; ++r) {
            int row = rowbase + t * 16 + quad * 4 + r;
            if (row < N_NODES)
              O8[(size_t)row * 256 + col] = f2fp8(acc[c4][t][r]);
          }
        }
      }
    } else {
      short* O = (mat == 0) ? Qo : So;
      #pragma unroll
      for (int c4 = 0; c4 < 4; ++c4) {
        const int col = ch * 64 + c4 * 16 + mm;
        #pragma unroll
        for (int t = 0; t < 2; ++t) {
          #pragma unroll
          for (int r = 0; r < 4; ++r) {
            int row = rowbase + t * 16 + quad * 4 + r;
            if (row < N_NODES)
              ((__hip_bfloat16*)O)[(size_t)row * 128 + col] = __float2bfloat16(acc[c4][t][r]);
          }
        }
      }
    }
  }
}

// ---------------- C1/C2: scan ----------------
__global__ __launch_bounds__(256)
void scan1(const int* __restrict__ cnt, int* __restrict__ offs, int* __restrict__ bsum) {
  __shared__ int wsum[4];
  int t = threadIdx.x, lane = t & 63, w = t >> 6;
  int i = blockIdx.x * 256 + t;
  int v = (i < N_NODES) ? cnt[i] : 0;
  int x = v;
  #pragma unroll
  for (int o = 1; o < 64; o <<= 1) { int y = __shfl_up(x, o, 64); if (lane >= o) x += y; }
  if (lane == 63) wsum[w] = x;
  __syncthreads();
  if (t == 0) {
    int run = 0;
    #pragma unroll
    for (int k = 0; k < 4; ++k) { int tv = wsum[k]; wsum[k] = run; run += tv; }
    bsum[blockIdx.x] = run;
  }
  __syncthreads();
  if (i <= N_NODES) offs[i] = wsum[w] + x - v;   // block-local exclusive prefix
}

__global__ __launch_bounds__(256)
void scan2(int* __restrict__ bsum) {
  __shared__ int wsum[4];
  int t = threadIdx.x, lane = t & 63, w = t >> 6;
  int v = (t < NB_SCAN) ? bsum[t] : 0;
  int x = v;
  #pragma unroll
  for (int o = 1; o < 64; o <<= 1) { int y = __shfl_up(x, o, 64); if (lane >= o) x += y; }
  if (lane == 63) wsum[w] = x;
  __syncthreads();
  if (t == 0) {
    int run = 0;
    #pragma unroll
    for (int k = 0; k < 4; ++k) { int tv = wsum[k]; wsum[k] = run; run += tv; }
  }
  __syncthreads();
  if (t < NB_SCAN) bsum[t] = wsum[w] + x - v;    // exclusive prefix of block sums
}

// ---------------- D: layer-1 gemm + atomic-free edge scatter fused (R1 form) ----------------
__global__ __launch_bounds__(256)
void scatter_gemm1(const int* __restrict__ ei, const int* __restrict__ offs,
                   const int* __restrict__ bsum, const unsigned short* __restrict__ rank,
                   int* __restrict__ ssrc,
                   const float* __restrict__ X,
                   const short* __restrict__ w1q, const short* __restrict__ w1k,
                   const short* __restrict__ w1v, const short* __restrict__ w1s,
                   const float* __restrict__ b1q, const float* __restrict__ b1k,
                   const float* __restrict__ b1v, const float* __restrict__ b1s,
                   short* Qb, unsigned char* KV8, short* Sb)
{
  __shared__ short lds[IN_CH * 128];   // 16 KB
  int bx = blockIdx.x;
  if (bx >= NB_GEMM) {
    int e0 = (bx - NB_GEMM) * 1024 + threadIdx.x * 4;
    if (e0 >= N_EDGES) return;
    if (e0 + 3 < N_EDGES) {
      int4 sv = *(const int4*)(ei + e0);
      int4 dv = *(const int4*)(ei + N_EDGES + e0);
      ushort4 rv = *(const ushort4*)(rank + e0);
      int d0 = clamp_id(dv.x), d1 = clamp_id(dv.y);
      int d2 = clamp_id(dv.z), d3 = clamp_id(dv.w);
      int p0 = offs[d0] + bsum[d0 >> 8] + rv.x;
      int p1 = offs[d1] + bsum[d1 >> 8] + rv.y;
      int p2 = offs[d2] + bsum[d2 >> 8] + rv.z;
      int p3 = offs[d3] + bsum[d3 >> 8] + rv.w;
      ssrc[p0] = clamp_id(sv.x);
      ssrc[p1] = clamp_id(sv.y);
      ssrc[p2] = clamp_id(sv.z);
      ssrc[p3] = clamp_id(sv.w);
    } else {
      for (int j = 0; j < 4; ++j) {
        int e = e0 + j;
        if (e < N_EDGES) {
          int src = clamp_id(ei[e]);
          int dst = clamp_id(ei[N_EDGES + e]);
          ssrc[offs[dst] + bsum[dst >> 8] + rank[e]] = src;
        }
      }
    }
    return;
  }
  gemm_body<IN_CH, 1>(bx, X, w1q, w1k, w1v, w1s, b1q, b1k, b1v, b1s,
                      Qb, KV8, Sb, lds);
}

// ---------------- attention (fp8 K/V, interleaved 256B rows) ----------------
// R5: 8 edge slots x 8 channel-lanes (uint4 K + uint4 V per lane) instead of
// 4 x 16 (uint2). Halves the serial iteration count per dst (avg deg 16 -> 2
// iters) and doubles per-iteration MLP; head-logit reduce is ONE shfl_xor(1)
// (each 8-lane row covers 16 channels; lane pairs span exactly one 32-ch head).
// No-max softmax in exp2 domain; 1-deep K/V register prefetch.
// H may alias S (in-place per dst row: the dst's own wave reads S before writing H).
__global__ __launch_bounds__(256)
void attn_kernel(const unsigned short* __restrict__ Q, const unsigned char* __restrict__ KV8,
                 const unsigned short* S,
                 const int* __restrict__ offs, const int* __restrict__ bsum,
                 const int* __restrict__ ssrc, unsigned short* H)
{
  const int dst = blockIdx.x * 4 + (threadIdx.x >> 6);
  if (dst >= N_NODES) return;               // wave-uniform
  const int lane = threadIdx.x & 63;
  const int sub  = lane >> 3;               // edge slot 0..7
  const int cl   = lane & 7;                // channel-lane: 16 channels each

  const float qs = 0.17677669529663687f * 1.4426950408889634f;  // 1/sqrt(32)*log2(e)
  const unsigned short* qp = Q + (size_t)dst * 128 + cl * 16;
  uint4 qw0 = *(const uint4*)(qp);
  uint4 qw1 = *(const uint4*)(qp + 8);
  float q[16], a[16];
  #pragma unroll
  for (int i = 0; i < 4; ++i) {
    unsigned w0 = ((unsigned*)&qw0)[i];
    q[2 * i]     = bfbits2f(w0 & 0xffffu) * qs;
    q[2 * i + 1] = bfhi2f(w0) * qs;
    unsigned w1 = ((unsigned*)&qw1)[i];
    q[8 + 2 * i]     = bfbits2f(w1 & 0xffffu) * qs;
    q[8 + 2 * i + 1] = bfhi2f(w1) * qs;
  }
  #pragma unroll
  for (int i = 0; i < 16; ++i) a[i] = 0.f;
  float s = 0.f;

  const int e0 = offs[dst] + bsum[dst >> 8];
  const int e1 = offs[dst + 1] + bsum[(dst + 1) >> 8];
  const int iters = (e1 - e0 + 7) >> 3;

  if (iters > 0) {
    int e = e0 + sub;
    bool have = (e < e1);
    int src = have ? ssrc[e] : ssrc[e0];
    float ph = have ? 1.f : 0.f;
    const unsigned char* kvp = KV8 + (size_t)src * 256 + cl * 16;
    uint4 kw = *(const uint4*)(kvp);
    uint4 vw = *(const uint4*)(kvp + 128);

    for (int it = 0; it < iters; ++it) {
      uint4 kwn, vwn;
      int en = e + 8;
      bool haven = (en < e1);
      float phn = haven ? 1.f : 0.f;
      if (it + 1 < iters) {                 // wave-uniform
        int srcn = haven ? ssrc[en] : ssrc[e0];
        const unsigned char* kvn = KV8 + (size_t)srcn * 256 + cl * 16;
        kwn = *(const uint4*)(kvn);
        vwn = *(const uint4*)(kvn + 128);
      } else {
        kwn = kw; vwn = vw;
      }
      float d = 0.f;
      #pragma unroll
      for (int i = 0; i < 4; ++i) {
        unsigned w = ((unsigned*)&kw)[i];
        f32x2 lo = fp8pair<false>(w), hi = fp8pair<true>(w);
        d += q[4 * i]     * lo.x + q[4 * i + 1] * lo.y
           + q[4 * i + 2] * hi.x + q[4 * i + 3] * hi.y;
      }
      d += __shfl_xor(d, 1, 64);            // head logit (head = cl>>1)
      float p = exp2f(d) * ph;
      s += p;
      #pragma unroll
      for (int i = 0; i < 4; ++i) {
        unsigned w = ((unsigned*)&vw)[i];
        f32x2 lo = fp8pair<false>(w), hi = fp8pair<true>(w);
        a[4 * i]     += p * lo.x; a[4 * i + 1] += p * lo.y;
        a[4 * i + 2] += p * hi.x; a[4 * i + 3] += p * hi.y;
      }
      kw = kwn; vw = vwn; ph = phn; e = en;
    }
  }

  s += __shfl_xor(s, 8, 64);
  s += __shfl_xor(s, 16, 64);
  s += __shfl_xor(s, 32, 64);
  #pragma unroll
  for (int i = 0; i < 16; ++i) {
    a[i] += __shfl_xor(a[i], 8, 64);
    a[i] += __shfl_xor(a[i], 16, 64);
    a[i] += __shfl_xor(a[i], 32, 64);
  }
  const float inv = (s > 0.f) ? (1.0f / s) : 0.f;

  if (sub == 0) {
    const unsigned short* sp = S + (size_t)dst * 128 + cl * 16;
    uint4 sw0 = *(const uint4*)(sp);
    uint4 sw1 = *(const uint4*)(sp + 8);
    uint4 ow0, ow1;
    #pragma unroll
    for (int i = 0; i < 4; ++i) {
      unsigned w0 = ((unsigned*)&sw0)[i];
      float o0 = fmaxf(a[2 * i] * inv     + bfbits2f(w0 & 0xffffu), 0.f);
      float o1 = fmaxf(a[2 * i + 1] * inv + bfhi2f(w0), 0.f);
      ((unsigned*)&ow0)[i] = (unsigned)f2bfu(o0) | ((unsigned)f2bfu(o1) << 16);
      unsigned w1 = ((unsigned*)&sw1)[i];
      float o2 = fmaxf(a[8 + 2 * i] * inv     + bfbits2f(w1 & 0xffffu), 0.f);
      float o3 = fmaxf(a[8 + 2 * i + 1] * inv + bfhi2f(w1), 0.f);
      ((unsigned*)&ow1)[i] = (unsigned)f2bfu(o2) | ((unsigned)f2bfu(o3) << 16);
    }
    unsigned short* hp = H + (size_t)dst * 128 + cl * 16;
    *(uint4*)(hp) = ow0;
    *(uint4*)(hp + 8) = ow1;
  }
}

// ---------------- F: layer-2 gemm ----------------
__global__ __launch_bounds__(256)
void gemm2(const short* __restrict__ X,
           const short* __restrict__ w2q, const short* __restrict__ w2k,
           const short* __restrict__ w2v, const short* __restrict__ w2s,
           const float* __restrict__ b2q, const float* __restrict__ b2k,
           const float* __restrict__ b2v, const float* __restrict__ b2s,
           short* Qb, unsigned char* KV8, short* Sb)
{
  __shared__ short lds[HID_CH * 128];  // 32 KB
  gemm_body<HID_CH, 0>(blockIdx.x, X, w2q, w2k, w2v, w2s, b2q, b2k, b2v, b2s,
                       Qb, KV8, Sb, lds);
}

// ---------------- pooling (16 partials/graph, few atomics) ----------------
__device__ __forceinline__ int lower_bound_i(const int* __restrict__ b, int n, int val) {
  int lo = 0, hi = n;
  while (lo < hi) { int mid = (lo + hi) >> 1; if (b[mid] < val) lo = mid + 1; else hi = mid; }
  return lo;
}

__global__ __launch_bounds__(128)
void pool_partial(const __hip_bfloat16* __restrict__ H, const int* __restrict__ batch,
                  float* __restrict__ pooled)
{
  const int g = blockIdx.x >> 4, p = blockIdx.x & 15, t = threadIdx.x;
  const int s = lower_bound_i(batch, N_NODES, g);
  const int e = lower_bound_i(batch, N_NODES, g + 1);
  const int len = e - s;
  if (len <= 0) return;
  const int chunk = (len + 15) >> 4;
  const int a = s + p * chunk;
  const int b = min(a + chunk, e);
  if (a >= b) return;
  float sum = 0.f;
  for (int i = a; i < b; ++i) sum += bf2f(H[(size_t)i * 128 + t]);
  atomicAdd(&pooled[g * 128 + t], sum);
}

__global__ __launch_bounds__(128)
void pool_final(const float* __restrict__ pooled, const int* __restrict__ batch,
                const float* __restrict__ Wl, const float* __restrict__ bl,
                float* __restrict__ out)
{
  const int g = blockIdx.x, t = threadIdx.x;
  __shared__ float r0[128], r1[128];
  const int s = lower_bound_i(batch, N_NODES, g);
  const int e = lower_bound_i(batch, N_NODES, g + 1);
  const float inv = 1.0f / (float)max(e - s, 1);
  const float pc = pooled[g * 128 + t] * inv;
  r0[t] = pc * Wl[t * 2 + 0];
  r1[t] = pc * Wl[t * 2 + 1];
  __syncthreads();
  for (int o = 64; o > 0; o >>= 1) {
    if (t < o) { r0[t] += r0[t + o]; r1[t] += r1[t + o]; }
    __syncthreads();
  }
  if (t == 0) {
    out[g * 2 + 0] = r0[0] + bl[0];
    out[g * 2 + 1] = r1[0] + bl[1];
  }
}

// ---------------- launch ----------------

extern "C" void kernel_launch(void* const* d_in, const int* in_sizes, int n_in,
                              void* d_out, int out_size, void* d_ws, size_t ws_size,
                              hipStream_t stream) {
  uintptr_t base = (uintptr_t)d_ws;
  auto take = [&](size_t bytes) -> uintptr_t {
    uintptr_t p = base;
    base += (bytes + 255) & ~(size_t)255;
    return p;
  };

  // cnt + pooled first and contiguous: zeroed by ONE hipMemsetAsync.
  int*   cnt    = (int*)take((size_t)N_NODES * 4);
  float* pooled = (float*)take((size_t)N_GRAPHS * 128 * 4);
  int*   offs   = (int*)take((size_t)(N_NODES + 1) * 4);
  int*   bsum   = (int*)take((size_t)NB_SCAN * 4);
  int*   ssrc   = (int*)take((size_t)N_EDGES * 4);
  unsigned short* rank = (unsigned short*)take((size_t)N_EDGES * 2);
  short* Qb     = (short*)take((size_t)N_NODES * 128 * 2);
  unsigned char* KV8 = (unsigned char*)take((size_t)N_NODES * 256);  // fp8 [K|V] rows
  short* Sb     = (short*)take((size_t)N_NODES * 128 * 2);  // S / H / layer-2 X (in-place)
  short* wt1q   = (short*)take((size_t)IN_CH * 128 * 2);
  short* wt1k   = (short*)take((size_t)IN_CH * 128 * 2);
  short* wt1v   = (short*)take((size_t)IN_CH * 128 * 2);
  short* wt1s   = (short*)take((size_t)IN_CH * 128 * 2);
  short* wt2q   = (short*)take((size_t)HID_CH * 128 * 2);
  short* wt2k   = (short*)take((size_t)HID_CH * 128 * 2);
  short* wt2v   = (short*)take((size_t)HID_CH * 128 * 2);
  short* wt2s   = (short*)take((size_t)HID_CH * 128 * 2);

  const int* ei    = (const int*)d_in[1];   // int32 per harness contract
  const int* batch = (const int*)d_in[2];   // int32 per harness contract

  // Zero cnt..pooled span (contiguous, one DMA memset; graph-capturable).
  size_t zspan = (size_t)((char*)pooled + (size_t)N_GRAPHS * 128 * 4 - (char*)cnt);
  hipMemsetAsync(cnt, 0, zspan, stream);

  // A: degree count + rank capture (blocks first) + weight canonicalization
  prep<<<NB_CNT4 + NB_CONV, 256, 0, stream>>>(
      ei, cnt, rank,
      (const float*)d_in[3], (const float*)d_in[5], (const float*)d_in[7], (const float*)d_in[9],
      (const float*)d_in[11], (const float*)d_in[13], (const float*)d_in[15], (const float*)d_in[17],
      (__hip_bfloat16*)wt1q, (__hip_bfloat16*)wt1k, (__hip_bfloat16*)wt1v, (__hip_bfloat16*)wt1s,
      (__hip_bfloat16*)wt2q, (__hip_bfloat16*)wt2k, (__hip_bfloat16*)wt2v, (__hip_bfloat16*)wt2s);

  // C: scan
  scan1<<<NB_SCAN, 256, 0, stream>>>(cnt, offs, bsum);
  scan2<<<1, 256, 0, stream>>>(bsum);

  // D: layer-1 QKVS gemm (blocks first) + atomic-free edge scatter (backfill)
  scatter_gemm1<<<NB_GEMM + NB_CNT4, 256, 0, stream>>>(
      ei, offs, bsum, rank, ssrc,
      (const float*)d_in[0],
      wt1q, wt1k, wt1v, wt1s,
      (const float*)d_in[4], (const float*)d_in[6], (const float*)d_in[8], (const float*)d_in[10],
      Qb, KV8, Sb);

  const int attn_grid = (N_NODES + 3) / 4;

  // E: layer-1 attention (writes H in place into Sb)
  attn_kernel<<<attn_grid, 256, 0, stream>>>(
      (const unsigned short*)Qb, KV8,
      (const unsigned short*)Sb, offs, bsum, ssrc, (unsigned short*)Sb);

  // F: layer-2 gemm (X = Sb, S in-place)
  gemm2<<<NB_GEMM, 256, 0, stream>>>(
      Sb, wt2q, wt2k, wt2v, wt2s,
      (const float*)d_in[12], (const float*)d_in[14], (const float*)d_in[16], (const float*)d_in[18],
      Qb, KV8, Sb);

  // G: layer-2 attention (writes H in place into Sb)
  attn_kernel<<<attn_grid, 256, 0, stream>>>(
      (const unsigned short*)Qb, KV8,
      (const unsigned short*)Sb, offs, bsum, ssrc, (unsigned short*)Sb);

  // Pool: 16 partials/graph -> one atomic per channel per partial, then final linear
  pool_partial<<<N_GRAPHS * 16, 128, 0, stream>>>(
      (const __hip_bfloat16*)Sb, batch, pooled);
  pool_final<<<N_GRAPHS, 128, 0, stream>>>(pooled, batch, (const float*)d_in[19],
                                           (const float*)d_in[20], (float*)d_out);
}

// Round 6
// 293.199 us; speedup vs baseline: 1.0539x; 1.0207x over previous
//
#include <hip/hip_runtime.h>
#include <hip/hip_bf16.h>
#include <cstdint>
#include <cstddef>

#define N_NODES 50000
#define N_EDGES 800000
#define IN_CH 64
#define HID_CH 128
#define N_GRAPHS 64

#define NB_SCAN ((N_NODES + 255) / 256)          // 196
#define NB_CNT4 ((N_EDGES + 1023) / 1024)        // 782 (4 edges/thread)
#define NB_GEMM ((N_NODES + 63) / 64)            // 782
#define W_ELEMS (4 * IN_CH * 128 + 4 * HID_CH * 128)  // 98304
#define NB_CONV ((W_ELEMS + 255) / 256)          // 384

typedef short s16x8 __attribute__((ext_vector_type(8)));
typedef float f32x4 __attribute__((ext_vector_type(4)));
typedef float f32x2 __attribute__((ext_vector_type(2)));

__device__ __forceinline__ float bf2f(__hip_bfloat16 v) { return __bfloat162float(v); }
__device__ __forceinline__ float bfbits2f(unsigned hs) {
  union { unsigned u; float f; } v; v.u = hs << 16; return v.f;
}
__device__ __forceinline__ float bfhi2f(unsigned w) {
  union { unsigned u; float f; } v; v.u = w & 0xffff0000u; return v.f;
}
__device__ __forceinline__ short f2bfs(float f) {
  __hip_bfloat16 h = __float2bfloat16(f); return *(short*)&h;
}
__device__ __forceinline__ unsigned short f2bfu(float f) {
  __hip_bfloat16 h = __float2bfloat16(f); return *(unsigned short*)&h;
}
__device__ __forceinline__ int clamp_id(int v) {
  if (v < 0) v = 0;
  if (v >= N_NODES) v = N_NODES - 1;
  return v;
}

// fp8 e4m3 (OCP) pack/unpack via gfx950 HW converters (word-selects are immediates).
__device__ __forceinline__ unsigned char f2fp8(float v) {
  return (unsigned char)(__builtin_amdgcn_cvt_pk_fp8_f32(v, v, 0, false) & 0xff);
}
template<bool HI>
__device__ __forceinline__ f32x2 fp8pair(unsigned w) {
  return __builtin_amdgcn_cvt_pk_f32_fp8(w, HI);
}

// R6: packed 2-wide f32 math (CDNA VOP3P). hipcc does not emit these from scalar
// source; non-volatile asm so the scheduler can interleave them freely.
__device__ __forceinline__ f32x2 pkfma(f32x2 a, f32x2 b, f32x2 c) {
  f32x2 d;
  asm("v_pk_fma_f32 %0, %1, %2, %3" : "=v"(d) : "v"(a), "v"(b), "v"(c));
  return d;
}
__device__ __forceinline__ f32x2 pkadd(f32x2 a, f32x2 b) {
  f32x2 d;
  asm("v_pk_add_f32 %0, %1, %2" : "=v"(d) : "v"(a), "v"(b));
  return d;
}

// ---------------- A: degree-count(+rank) + weight canonicalization ----------------
// (R1-verified: cnt zeroed by hipMemsetAsync; atomicAdd return value saved as the
// edge's intra-segment rank so the scatter needs no second atomic round.)
__global__ __launch_bounds__(256)
void prep(const int* __restrict__ ei, int* __restrict__ cnt,
          unsigned short* __restrict__ rank,
          const float* __restrict__ w1q, const float* __restrict__ w1k,
          const float* __restrict__ w1v, const float* __restrict__ w1s,
          const float* __restrict__ w2q, const float* __restrict__ w2k,
          const float* __restrict__ w2v, const float* __restrict__ w2s,
          __hip_bfloat16* d1q, __hip_bfloat16* d1k, __hip_bfloat16* d1v, __hip_bfloat16* d1s,
          __hip_bfloat16* d2q, __hip_bfloat16* d2k, __hip_bfloat16* d2v, __hip_bfloat16* d2s)
{
  int bx = blockIdx.x;
  if (bx < NB_CNT4) {
    int e0 = bx * 1024 + threadIdx.x * 4;
    if (e0 >= N_EDGES) return;
    if (e0 + 3 < N_EDGES) {
      int4 dv = *(const int4*)(ei + N_EDGES + e0);
      unsigned short r0 = (unsigned short)atomicAdd(&cnt[clamp_id(dv.x)], 1);
      unsigned short r1 = (unsigned short)atomicAdd(&cnt[clamp_id(dv.y)], 1);
      unsigned short r2 = (unsigned short)atomicAdd(&cnt[clamp_id(dv.z)], 1);
      unsigned short r3 = (unsigned short)atomicAdd(&cnt[clamp_id(dv.w)], 1);
      ushort4 rv; rv.x = r0; rv.y = r1; rv.z = r2; rv.w = r3;
      *(ushort4*)(rank + e0) = rv;
    } else {
      for (int j = 0; j < 4; ++j)
        if (e0 + j < N_EDGES)
          rank[e0 + j] = (unsigned short)atomicAdd(&cnt[clamp_id(ei[N_EDGES + e0 + j])], 1);
    }
    return;
  }
  int j = (bx - NB_CNT4) * 256 + threadIdx.x;
  if (j >= W_ELEMS) return;
  const float* S[8] = {w1q, w1k, w1v, w1s, w2q, w2k, w2v, w2s};
  __hip_bfloat16* D[8] = {d1q, d1k, d1v, d1s, d2q, d2k, d2v, d2s};
  int m, r;
  if (j < 4 * IN_CH * 128) { m = j >> 13; r = j & 8191; }
  else { int jj = j - 4 * IN_CH * 128; m = 4 + (jj >> 14); r = jj & 16383; }
  int k = r >> 7, c = r & 127;
  D[m][(((k >> 3) * 128 + c) << 3) + (k & 7)] = __float2bfloat16(S[m][r]);
}

// ---------------- shared gemm body (R1-verified: 4-mat loop, direct stores) ----------------
// Outputs: mat0=Q (bf16, row 128), mat1=K -> KV8 row byte [0..128), mat2=V -> KV8 [128..256),
// mat3=S (bf16, row 128). KV8 row = 256 bytes, fp8 e4m3.
// So may alias X (in-place per-row: A-frags register-resident before stores).
// R2 (LDS-bounce stores), R3 (per-mat blocks), R4 (ROWG pipeline) all regressed vs this.
template<int KD, int XF32>
__device__ __forceinline__ void gemm_body(
    int bg, const void* X,
    const short* __restrict__ WTq, const short* __restrict__ WTk,
    const short* __restrict__ WTv, const short* __restrict__ WTs,
    const float* __restrict__ bq, const float* __restrict__ bk,
    const float* __restrict__ bv, const float* __restrict__ bs,
    short* Qo, unsigned char* KV8, short* So, short* lds)
{
  constexpr int KT = KD / 32;
  constexpr int CHUNKS = KD * 16;
  const int tid  = threadIdx.x;
  const int wid  = tid >> 6;
  const int lane = tid & 63;
  const int quad = lane >> 4;
  const int mm   = lane & 15;
  const int rt   = wid & 1;
  const int ch   = wid >> 1;
  const int rowbase = bg * 64 + rt * 32;

  s16x8 afrag[2][KT];
  #pragma unroll
  for (int t = 0; t < 2; ++t) {
    const int arow = rowbase + t * 16 + mm;
    if (arow < N_NODES) {
      if (XF32) {
        const float* xp = (const float*)X + (size_t)arow * KD;
        #pragma unroll
        for (int kt = 0; kt < KT; ++kt) {
          const float4* p = (const float4*)(xp + kt * 32 + quad * 8);
          float4 a = p[0], b = p[1];
          s16x8 fr;
          fr[0] = f2bfs(a.x); fr[1] = f2bfs(a.y); fr[2] = f2bfs(a.z); fr[3] = f2bfs(a.w);
          fr[4] = f2bfs(b.x); fr[5] = f2bfs(b.y); fr[6] = f2bfs(b.z); fr[7] = f2bfs(b.w);
          afrag[t][kt] = fr;
        }
      } else {
        const short* xp = (const short*)X + (size_t)arow * KD;
        #pragma unroll
        for (int kt = 0; kt < KT; ++kt)
          afrag[t][kt] = *(const s16x8*)(xp + kt * 32 + quad * 8);
      }
    } else {
      #pragma unroll
      for (int kt = 0; kt < KT; ++kt)
        afrag[t][kt] = (s16x8){0,0,0,0,0,0,0,0};
    }
  }

  const short* wts[4] = {WTq, WTk, WTv, WTs};
  const float* bias[4] = {bq, bk, bv, bs};

  #pragma unroll
  for (int mat = 0; mat < 4; ++mat) {
    if (mat > 0) __syncthreads();
    {
      const uint4* src = (const uint4*)wts[mat];
      uint4* dst = (uint4*)lds;
      #pragma unroll
      for (int i = 0; i < CHUNKS / 256; ++i)
        dst[tid + i * 256] = src[tid + i * 256];
    }
    __syncthreads();

    f32x4 acc[4][2];
    #pragma unroll
    for (int c4 = 0; c4 < 4; ++c4) {
      float b = bias[mat][ch * 64 + c4 * 16 + mm];
      f32x4 av = {b, b, b, b};
      acc[c4][0] = av; acc[c4][1] = av;
    }
    #pragma unroll
    for (int kt = 0; kt < KT; ++kt) {
      #pragma unroll
      for (int c4 = 0; c4 < 4; ++c4) {
        s16x8 bfrag = *(const s16x8*)(lds + ((((kt * 4 + quad) << 7) + ch * 64 + c4 * 16 + mm) << 3));
        acc[c4][0] = __builtin_amdgcn_mfma_f32_16x16x32_bf16(afrag[0][kt], bfrag, acc[c4][0], 0, 0, 0);
        acc[c4][1] = __builtin_amdgcn_mfma_f32_16x16x32_bf16(afrag[1][kt], bfrag, acc[c4][1], 0, 0, 0);
      }
    }
    if (mat == 1 || mat == 2) {
      unsigned char* O8 = KV8 + ((mat == 1) ? 0 : 128);
      #pragma unroll
      for (int c4 = 0; c4 < 4; ++c4) {
        const int col = ch * 64 + c4 * 16 + mm;
        #pragma unroll
        for (int t = 0; t < 2; ++t) {
          #pragma unroll
          for (int r = 0; r < 4; ++r) {
            int row = rowbase + t * 16 + quad * 4 + r;
            if (row < N_NODES)
              O8[(size_t)row * 256 + col] = f2fp8(acc[c4][t][r]);
          }
        }
      }
    } else {
      short* O = (mat == 0) ? Qo : So;
      #pragma unroll
      for (int c4 = 0; c4 < 4; ++c4) {
        const int col = ch * 64 + c4 * 16 + mm;
        #pragma unroll
        for (int t = 0; t < 2; ++t) {
          #pragma unroll
          for (int r = 0; r < 4; ++r) {
            int row = rowbase + t * 16 + quad * 4 + r;
            if (row < N_NODES)
              ((__hip_bfloat16*)O)[(size_t)row * 128 + col] = __float2bfloat16(acc[c4][t][r]);
          }
        }
      }
    }
  }
}

// ---------------- C1/C2: scan ----------------
__global__ __launch_bounds__(256)
void scan1(const int* __restrict__ cnt, int* __restrict__ offs, int* __restrict__ bsum) {
  __shared__ int wsum[4];
  int t = threadIdx.x, lane = t & 63, w = t >> 6;
  int i = blockIdx.x * 256 + t;
  int v = (i < N_NODES) ? cnt[i] : 0;
  int x = v;
  #pragma unroll
  for (int o = 1; o < 64; o <<= 1) { int y = __shfl_up(x, o, 64); if (lane >= o) x += y; }
  if (lane == 63) wsum[w] = x;
  __syncthreads();
  if (t == 0) {
    int run = 0;
    #pragma unroll
    for (int k = 0; k < 4; ++k) { int tv = wsum[k]; wsum[k] = run; run += tv; }
    bsum[blockIdx.x] = run;
  }
  __syncthreads();
  if (i <= N_NODES) offs[i] = wsum[w] + x - v;   // block-local exclusive prefix
}

__global__ __launch_bounds__(256)
void scan2(int* __restrict__ bsum) {
  __shared__ int wsum[4];
  int t = threadIdx.x, lane = t & 63, w = t >> 6;
  int v = (t < NB_SCAN) ? bsum[t] : 0;
  int x = v;
  #pragma unroll
  for (int o = 1; o < 64; o <<= 1) { int y = __shfl_up(x, o, 64); if (lane >= o) x += y; }
  if (lane == 63) wsum[w] = x;
  __syncthreads();
  if (t == 0) {
    int run = 0;
    #pragma unroll
    for (int k = 0; k < 4; ++k) { int tv = wsum[k]; wsum[k] = run; run += tv; }
  }
  __syncthreads();
  if (t < NB_SCAN) bsum[t] = wsum[w] + x - v;    // exclusive prefix of block sums
}

// ---------------- D: layer-1 gemm + atomic-free edge scatter fused (R1 form) ----------------
__global__ __launch_bounds__(256)
void scatter_gemm1(const int* __restrict__ ei, const int* __restrict__ offs,
                   const int* __restrict__ bsum, const unsigned short* __restrict__ rank,
                   int* __restrict__ ssrc,
                   const float* __restrict__ X,
                   const short* __restrict__ w1q, const short* __restrict__ w1k,
                   const short* __restrict__ w1v, const short* __restrict__ w1s,
                   const float* __restrict__ b1q, const float* __restrict__ b1k,
                   const float* __restrict__ b1v, const float* __restrict__ b1s,
                   short* Qb, unsigned char* KV8, short* Sb)
{
  __shared__ short lds[IN_CH * 128];   // 16 KB
  int bx = blockIdx.x;
  if (bx >= NB_GEMM) {
    int e0 = (bx - NB_GEMM) * 1024 + threadIdx.x * 4;
    if (e0 >= N_EDGES) return;
    if (e0 + 3 < N_EDGES) {
      int4 sv = *(const int4*)(ei + e0);
      int4 dv = *(const int4*)(ei + N_EDGES + e0);
      ushort4 rv = *(const ushort4*)(rank + e0);
      int d0 = clamp_id(dv.x), d1 = clamp_id(dv.y);
      int d2 = clamp_id(dv.z), d3 = clamp_id(dv.w);
      int p0 = offs[d0] + bsum[d0 >> 8] + rv.x;
      int p1 = offs[d1] + bsum[d1 >> 8] + rv.y;
      int p2 = offs[d2] + bsum[d2 >> 8] + rv.z;
      int p3 = offs[d3] + bsum[d3 >> 8] + rv.w;
      ssrc[p0] = clamp_id(sv.x);
      ssrc[p1] = clamp_id(sv.y);
      ssrc[p2] = clamp_id(sv.z);
      ssrc[p3] = clamp_id(sv.w);
    } else {
      for (int j = 0; j < 4; ++j) {
        int e = e0 + j;
        if (e < N_EDGES) {
          int src = clamp_id(ei[e]);
          int dst = clamp_id(ei[N_EDGES + e]);
          ssrc[offs[dst] + bsum[dst >> 8] + rank[e]] = src;
        }
      }
    }
    return;
  }
  gemm_body<IN_CH, 1>(bx, X, w1q, w1k, w1v, w1s, b1q, b1k, b1v, b1s,
                      Qb, KV8, Sb, lds);
}

// ---------------- attention (fp8 K/V, interleaved 256B rows) ----------------
// R6: back to R1's 4 edge slots x 16 channel-lanes (fits the 64-VGPR/8-wave budget;
// R5's 8x8 with q[16]/a[16] spilled: VGPR_Count 40 < ~60 live), with the inner math
// in v_pk_fma_f32/v_pk_add_f32 (2 FLOPs/inst) — R5 counters showed attn VALU-bound
// (VALUBusy 74%, MfmaUtil 0, occupancy 48%).
// No-max softmax in exp2 domain; 1-deep K/V register prefetch.
// H may alias S (in-place per dst row: the dst's own wave reads S before writing H).
__global__ __launch_bounds__(256)
void attn_kernel(const unsigned short* __restrict__ Q, const unsigned char* __restrict__ KV8,
                 const unsigned short* S,
                 const int* __restrict__ offs, const int* __restrict__ bsum,
                 const int* __restrict__ ssrc, unsigned short* H)
{
  const int dst = blockIdx.x * 4 + (threadIdx.x >> 6);
  if (dst >= N_NODES) return;               // wave-uniform
  const int lane = threadIdx.x & 63;
  const int sub  = lane >> 4;               // edge slot 0..3
  const int cl   = lane & 15;               // 8 channels per lane

  const float qs = 0.17677669529663687f * 1.4426950408889634f;  // 1/sqrt(32)*log2(e)
  uint4 qw = *(const uint4*)(Q + (size_t)dst * 128 + cl * 8);
  f32x2 q2[4], a2[4];
  #pragma unroll
  for (int i = 0; i < 4; ++i) {
    unsigned w = ((unsigned*)&qw)[i];
    f32x2 t; t.x = bfbits2f(w & 0xffffu) * qs; t.y = bfhi2f(w) * qs;
    q2[i] = t;
    a2[i].x = 0.f; a2[i].y = 0.f;
  }
  float s = 0.f;

  const int e0 = offs[dst] + bsum[dst >> 8];
  const int e1 = offs[dst + 1] + bsum[(dst + 1) >> 8];
  const int iters = (e1 - e0 + 3) >> 2;

  if (iters > 0) {
    int e = e0 + sub;
    bool have = (e < e1);
    int src = have ? ssrc[e] : ssrc[e0];
    float ph = have ? 1.f : 0.f;
    const unsigned char* kvp = KV8 + (size_t)src * 256 + cl * 8;
    uint2 kw = *(const uint2*)(kvp);
    uint2 vw = *(const uint2*)(kvp + 128);

    for (int it = 0; it < iters; ++it) {
      uint2 kwn, vwn;
      int en = e + 4;
      bool haven = (en < e1);
      float phn = haven ? 1.f : 0.f;
      if (it + 1 < iters) {                 // wave-uniform
        int srcn = haven ? ssrc[en] : ssrc[e0];
        const unsigned char* kvn = KV8 + (size_t)srcn * 256 + cl * 8;
        kwn = *(const uint2*)(kvn);
        vwn = *(const uint2*)(kvn + 128);
      } else {
        kwn = kw; vwn = vw;
      }
      f32x2 k0 = fp8pair<false>(kw.x), k1 = fp8pair<true>(kw.x);
      f32x2 k2 = fp8pair<false>(kw.y), k3 = fp8pair<true>(kw.y);
      f32x2 zz; zz.x = 0.f; zz.y = 0.f;
      f32x2 dd = pkfma(q2[0], k0, zz);
      dd = pkfma(q2[1], k1, dd);
      dd = pkfma(q2[2], k2, dd);
      dd = pkfma(q2[3], k3, dd);
      float d = dd.x + dd.y;
      d += __shfl_xor(d, 1, 64);
      d += __shfl_xor(d, 2, 64);
      float p = exp2f(d) * ph;
      s += p;
      f32x2 p2; p2.x = p; p2.y = p;
      f32x2 v0 = fp8pair<false>(vw.x), v1 = fp8pair<true>(vw.x);
      f32x2 v2 = fp8pair<false>(vw.y), v3 = fp8pair<true>(vw.y);
      a2[0] = pkfma(p2, v0, a2[0]);
      a2[1] = pkfma(p2, v1, a2[1]);
      a2[2] = pkfma(p2, v2, a2[2]);
      a2[3] = pkfma(p2, v3, a2[3]);
      kw = kwn; vw = vwn; ph = phn; e = en;
    }
  }

  s += __shfl_xor(s, 16, 64);
  s += __shfl_xor(s, 32, 64);
  #pragma unroll
  for (int i = 0; i < 4; ++i) {
    f32x2 t;
    t.x = __shfl_xor(a2[i].x, 16, 64);
    t.y = __shfl_xor(a2[i].y, 16, 64);
    a2[i] = pkadd(a2[i], t);
    t.x = __shfl_xor(a2[i].x, 32, 64);
    t.y = __shfl_xor(a2[i].y, 32, 64);
    a2[i] = pkadd(a2[i], t);
  }
  const float inv = (s > 0.f) ? (1.0f / s) : 0.f;

  if (sub == 0) {
    uint4 sw = *(const uint4*)(S + (size_t)dst * 128 + cl * 8);
    uint4 ow;
    #pragma unroll
    for (int i = 0; i < 4; ++i) {
      unsigned w = ((unsigned*)&sw)[i];
      float o0 = fmaxf(a2[i].x * inv + bfbits2f(w & 0xffffu), 0.f);
      float o1 = fmaxf(a2[i].y * inv + bfhi2f(w), 0.f);
      ((unsigned*)&ow)[i] = (unsigned)f2bfu(o0) | ((unsigned)f2bfu(o1) << 16);
    }
    *(uint4*)(H + (size_t)dst * 128 + cl * 8) = ow;
  }
}

// ---------------- F: layer-2 gemm ----------------
__global__ __launch_bounds__(256)
void gemm2(const short* __restrict__ X,
           const short* __restrict__ w2q, const short* __restrict__ w2k,
           const short* __restrict__ w2v, const short* __restrict__ w2s,
           const float* __restrict__ b2q, const float* __restrict__ b2k,
           const float* __restrict__ b2v, const float* __restrict__ b2s,
           short* Qb, unsigned char* KV8, short* Sb)
{
  __shared__ short lds[HID_CH * 128];  // 32 KB
  gemm_body<HID_CH, 0>(blockIdx.x, X, w2q, w2k, w2v, w2s, b2q, b2k, b2v, b2s,
                       Qb, KV8, Sb, lds);
}

// ---------------- pooling (16 partials/graph, few atomics) ----------------
__device__ __forceinline__ int lower_bound_i(const int* __restrict__ b, int n, int val) {
  int lo = 0, hi = n;
  while (lo < hi) { int mid = (lo + hi) >> 1; if (b[mid] < val) lo = mid + 1; else hi = mid; }
  return lo;
}

__global__ __launch_bounds__(128)
void pool_partial(const __hip_bfloat16* __restrict__ H, const int* __restrict__ batch,
                  float* __restrict__ pooled)
{
  const int g = blockIdx.x >> 4, p = blockIdx.x & 15, t = threadIdx.x;
  const int s = lower_bound_i(batch, N_NODES, g);
  const int e = lower_bound_i(batch, N_NODES, g + 1);
  const int len = e - s;
  if (len <= 0) return;
  const int chunk = (len + 15) >> 4;
  const int a = s + p * chunk;
  const int b = min(a + chunk, e);
  if (a >= b) return;
  float sum = 0.f;
  for (int i = a; i < b; ++i) sum += bf2f(H[(size_t)i * 128 + t]);
  atomicAdd(&pooled[g * 128 + t], sum);
}

__global__ __launch_bounds__(128)
void pool_final(const float* __restrict__ pooled, const int* __restrict__ batch,
                const float* __restrict__ Wl, const float* __restrict__ bl,
                float* __restrict__ out)
{
  const int g = blockIdx.x, t = threadIdx.x;
  __shared__ float r0[128], r1[128];
  const int s = lower_bound_i(batch, N_NODES, g);
  const int e = lower_bound_i(batch, N_NODES, g + 1);
  const float inv = 1.0f / (float)max(e - s, 1);
  const float pc = pooled[g * 128 + t] * inv;
  r0[t] = pc * Wl[t * 2 + 0];
  r1[t] = pc * Wl[t * 2 + 1];
  __syncthreads();
  for (int o = 64; o > 0; o >>= 1) {
    if (t < o) { r0[t] += r0[t + o]; r1[t] += r1[t + o]; }
    __syncthreads();
  }
  if (t == 0) {
    out[g * 2 + 0] = r0[0] + bl[0];
    out[g * 2 + 1] = r1[0] + bl[1];
  }
}

// ---------------- launch ----------------

extern "C" void kernel_launch(void* const* d_in, const int* in_sizes, int n_in,
                              void* d_out, int out_size, void* d_ws, size_t ws_size,
                              hipStream_t stream) {
  uintptr_t base = (uintptr_t)d_ws;
  auto take = [&](size_t bytes) -> uintptr_t {
    uintptr_t p = base;
    base += (bytes + 255) & ~(size_t)255;
    return p;
  };

  // cnt + pooled first and contiguous: zeroed by ONE hipMemsetAsync.
  int*   cnt    = (int*)take((size_t)N_NODES * 4);
  float* pooled = (float*)take((size_t)N_GRAPHS * 128 * 4);
  int*   offs   = (int*)take((size_t)(N_NODES + 1) * 4);
  int*   bsum   = (int*)take((size_t)NB_SCAN * 4);
  int*   ssrc   = (int*)take((size_t)N_EDGES * 4);
  unsigned short* rank = (unsigned short*)take((size_t)N_EDGES * 2);
  short* Qb     = (short*)take((size_t)N_NODES * 128 * 2);
  unsigned char* KV8 = (unsigned char*)take((size_t)N_NODES * 256);  // fp8 [K|V] rows
  short* Sb     = (short*)take((size_t)N_NODES * 128 * 2);  // S / H / layer-2 X (in-place)
  short* wt1q   = (short*)take((size_t)IN_CH * 128 * 2);
  short* wt1k   = (short*)take((size_t)IN_CH * 128 * 2);
  short* wt1v   = (short*)take((size_t)IN_CH * 128 * 2);
  short* wt1s   = (short*)take((size_t)IN_CH * 128 * 2);
  short* wt2q   = (short*)take((size_t)HID_CH * 128 * 2);
  short* wt2k   = (short*)take((size_t)HID_CH * 128 * 2);
  short* wt2v   = (short*)take((size_t)HID_CH * 128 * 2);
  short* wt2s   = (short*)take((size_t)HID_CH * 128 * 2);

  const int* ei    = (const int*)d_in[1];   // int32 per harness contract
  const int* batch = (const int*)d_in[2];   // int32 per harness contract

  // Zero cnt..pooled span (contiguous, one DMA memset; graph-capturable).
  size_t zspan = (size_t)((char*)pooled + (size_t)N_GRAPHS * 128 * 4 - (char*)cnt);
  hipMemsetAsync(cnt, 0, zspan, stream);

  // A: degree count + rank capture (blocks first) + weight canonicalization
  prep<<<NB_CNT4 + NB_CONV, 256, 0, stream>>>(
      ei, cnt, rank,
      (const float*)d_in[3], (const float*)d_in[5], (const float*)d_in[7], (const float*)d_in[9],
      (const float*)d_in[11], (const float*)d_in[13], (const float*)d_in[15], (const float*)d_in[17],
      (__hip_bfloat16*)wt1q, (__hip_bfloat16*)wt1k, (__hip_bfloat16*)wt1v, (__hip_bfloat16*)wt1s,
      (__hip_bfloat16*)wt2q, (__hip_bfloat16*)wt2k, (__hip_bfloat16*)wt2v, (__hip_bfloat16*)wt2s);

  // C: scan
  scan1<<<NB_SCAN, 256, 0, stream>>>(cnt, offs, bsum);
  scan2<<<1, 256, 0, stream>>>(bsum);

  // D: layer-1 QKVS gemm (blocks first) + atomic-free edge scatter (backfill)
  scatter_gemm1<<<NB_GEMM + NB_CNT4, 256, 0, stream>>>(
      ei, offs, bsum, rank, ssrc,
      (const float*)d_in[0],
      wt1q, wt1k, wt1v, wt1s,
      (const float*)d_in[4], (const float*)d_in[6], (const float*)d_in[8], (const float*)d_in[10],
      Qb, KV8, Sb);

  const int attn_grid = (N_NODES + 3) / 4;

  // E: layer-1 attention (writes H in place into Sb)
  attn_kernel<<<attn_grid, 256, 0, stream>>>(
      (const unsigned short*)Qb, KV8,
      (const unsigned short*)Sb, offs, bsum, ssrc, (unsigned short*)Sb);

  // F: layer-2 gemm (X = Sb, S in-place)
  gemm2<<<NB_GEMM, 256, 0, stream>>>(
      Sb, wt2q, wt2k, wt2v, wt2s,
      (const float*)d_in[12], (const float*)d_in[14], (const float*)d_in[16], (const float*)d_in[18],
      Qb, KV8, Sb);

  // G: layer-2 attention (writes H in place into Sb)
  attn_kernel<<<attn_grid, 256, 0, stream>>>(
      (const unsigned short*)Qb, KV8,
      (const unsigned short*)Sb, offs, bsum, ssrc, (unsigned short*)Sb);

  // Pool: 16 partials/graph -> one atomic per channel per partial, then final linear
  pool_partial<<<N_GRAPHS * 16, 128, 0, stream>>>(
      (const __hip_bfloat16*)Sb, batch, pooled);
  pool_final<<<N_GRAPHS, 128, 0, stream>>>(pooled, batch, (const float*)d_in[19],
                                           (const float*)d_in[20], (float*)d_out);
}

// Round 8
// 292.306 us; speedup vs baseline: 1.0571x; 1.0031x over previous
//
#include <hip/hip_runtime.h>
#include <hip/hip_bf16.h>
#include <cstdint>
#include <cstddef>

#define N_NODES 50000
#define N_EDGES 800000
#define IN_CH 64
#define HID_CH 128
#define N_GRAPHS 64

#define NB_SCAN ((N_NODES + 255) / 256)          // 196
#define NB_CNT4 ((N_EDGES + 1023) / 1024)        // 782 (4 edges/thread)
#define NB_GEMM ((N_NODES + 63) / 64)            // 782
#define W_ELEMS (4 * IN_CH * 128 + 4 * HID_CH * 128)  // 98304
#define NB_CONV ((W_ELEMS + 255) / 256)          // 384

typedef short s16x8 __attribute__((ext_vector_type(8)));
typedef float f32x4 __attribute__((ext_vector_type(4)));
typedef float f32x2 __attribute__((ext_vector_type(2)));

__device__ __forceinline__ float bf2f(__hip_bfloat16 v) { return __bfloat162float(v); }
__device__ __forceinline__ float bfbits2f(unsigned hs) {
  union { unsigned u; float f; } v; v.u = hs << 16; return v.f;
}
__device__ __forceinline__ float bfhi2f(unsigned w) {
  union { unsigned u; float f; } v; v.u = w & 0xffff0000u; return v.f;
}
__device__ __forceinline__ short f2bfs(float f) {
  __hip_bfloat16 h = __float2bfloat16(f); return *(short*)&h;
}
__device__ __forceinline__ unsigned short f2bfu(float f) {
  __hip_bfloat16 h = __float2bfloat16(f); return *(unsigned short*)&h;
}
__device__ __forceinline__ int clamp_id(int v) {
  if (v < 0) v = 0;
  if (v >= N_NODES) v = N_NODES - 1;
  return v;
}

// fp8 e4m3 (OCP) pack/unpack via gfx950 HW converters (word-selects are immediates).
__device__ __forceinline__ unsigned char f2fp8(float v) {
  return (unsigned char)(__builtin_amdgcn_cvt_pk_fp8_f32(v, v, 0, false) & 0xff);
}
template<bool HI>
__device__ __forceinline__ f32x2 fp8pair(unsigned w) {
  return __builtin_amdgcn_cvt_pk_f32_fp8(w, HI);
}

// R6: packed 2-wide f32 math (CDNA VOP3P). hipcc does not emit these from scalar
// source; non-volatile asm so the scheduler can interleave them freely.
__device__ __forceinline__ f32x2 pkfma(f32x2 a, f32x2 b, f32x2 c) {
  f32x2 d;
  asm("v_pk_fma_f32 %0, %1, %2, %3" : "=v"(d) : "v"(a), "v"(b), "v"(c));
  return d;
}
__device__ __forceinline__ f32x2 pkadd(f32x2 a, f32x2 b) {
  f32x2 d;
  asm("v_pk_add_f32 %0, %1, %2" : "=v"(d) : "v"(a), "v"(b));
  return d;
}

// R7: 4-lane quad sum on the VALU via DPP quad_perm (builtin -> compiler handles
// DPP read-after-VALU hazards). Replaces 2x __shfl_xor = 2x ds_bpermute (~30cy
// LDS-pipe latency each + lgkmcnt wait) sitting in the per-edge dependent chain.
// quad_perm encodings: [1,0,3,2] = 0xB1, [2,3,0,1] = 0x4E. (Hand-verified R7pm.)
__device__ __forceinline__ float quad_sum(float d) {
  d += __int_as_float(__builtin_amdgcn_mov_dpp(__float_as_int(d), 0xB1, 0xf, 0xf, true));
  d += __int_as_float(__builtin_amdgcn_mov_dpp(__float_as_int(d), 0x4E, 0xf, 0xf, true));
  return d;
}

// ---------------- A: degree-count(+rank) + weight canonicalization ----------------
// (R1-verified: cnt zeroed by hipMemsetAsync; atomicAdd return value saved as the
// edge's intra-segment rank so the scatter needs no second atomic round.)
__global__ __launch_bounds__(256)
void prep(const int* __restrict__ ei, int* __restrict__ cnt,
          unsigned short* __restrict__ rank,
          const float* __restrict__ w1q, const float* __restrict__ w1k,
          const float* __restrict__ w1v, const float* __restrict__ w1s,
          const float* __restrict__ w2q, const float* __restrict__ w2k,
          const float* __restrict__ w2v, const float* __restrict__ w2s,
          __hip_bfloat16* d1q, __hip_bfloat16* d1k, __hip_bfloat16* d1v, __hip_bfloat16* d1s,
          __hip_bfloat16* d2q, __hip_bfloat16* d2k, __hip_bfloat16* d2v, __hip_bfloat16* d2s)
{
  int bx = blockIdx.x;
  if (bx < NB_CNT4) {
    int e0 = bx * 1024 + threadIdx.x * 4;
    if (e0 >= N_EDGES) return;
    if (e0 + 3 < N_EDGES) {
      int4 dv = *(const int4*)(ei + N_EDGES + e0);
      unsigned short r0 = (unsigned short)atomicAdd(&cnt[clamp_id(dv.x)], 1);
      unsigned short r1 = (unsigned short)atomicAdd(&cnt[clamp_id(dv.y)], 1);
      unsigned short r2 = (unsigned short)atomicAdd(&cnt[clamp_id(dv.z)], 1);
      unsigned short r3 = (unsigned short)atomicAdd(&cnt[clamp_id(dv.w)], 1);
      ushort4 rv; rv.x = r0; rv.y = r1; rv.z = r2; rv.w = r3;
      *(ushort4*)(rank + e0) = rv;
    } else {
      for (int j = 0; j < 4; ++j)
        if (e0 + j < N_EDGES)
          rank[e0 + j] = (unsigned short)atomicAdd(&cnt[clamp_id(ei[N_EDGES + e0 + j])], 1);
    }
    return;
  }
  int j = (bx - NB_CNT4) * 256 + threadIdx.x;
  if (j >= W_ELEMS) return;
  const float* S[8] = {w1q, w1k, w1v, w1s, w2q, w2k, w2v, w2s};
  __hip_bfloat16* D[8] = {d1q, d1k, d1v, d1s, d2q, d2k, d2v, d2s};
  int m, r;
  if (j < 4 * IN_CH * 128) { m = j >> 13; r = j & 8191; }
  else { int jj = j - 4 * IN_CH * 128; m = 4 + (jj >> 14); r = jj & 16383; }
  int k = r >> 7, c = r & 127;
  D[m][(((k >> 3) * 128 + c) << 3) + (k & 7)] = __float2bfloat16(S[m][r]);
}

// ---------------- shared gemm body (R1-verified: 4-mat loop, direct stores) ----------------
// Outputs: mat0=Q (bf16, row 128), mat1=K, mat2=V -> KV8 row, mat3=S (bf16, row 128).
// R7: KV8 row is INTERLEAVED in 16B groups: byte 16*g+0..7 = K ch 8g..8g+7,
// byte 16*g+8..15 = V same channels -> attn reads K+V with ONE uint4/lane
// (kv.x/kv.y = K pairs, kv.z/kv.w = V pairs — the R7 fail had these crossed).
// So may alias X (in-place per-row: A-frags register-resident before stores).
template<int KD, int XF32>
__device__ __forceinline__ void gemm_body(
    int bg, const void* X,
    const short* __restrict__ WTq, const short* __restrict__ WTk,
    const short* __restrict__ WTv, const short* __restrict__ WTs,
    const float* __restrict__ bq, const float* __restrict__ bk,
    const float* __restrict__ bv, const float* __restrict__ bs,
    short* Qo, unsigned char* KV8, short* So, short* lds)
{
  constexpr int KT = KD / 32;
  constexpr int CHUNKS = KD * 16;
  const int tid  = threadIdx.x;
  const int wid  = tid >> 6;
  const int lane = tid & 63;
  const int quad = lane >> 4;
  const int mm   = lane & 15;
  const int rt   = wid & 1;
  const int ch   = wid >> 1;
  const int rowbase = bg * 64 + rt * 32;

  s16x8 afrag[2][KT];
  #pragma unroll
  for (int t = 0; t < 2; ++t) {
    const int arow = rowbase + t * 16 + mm;
    if (arow < N_NODES) {
      if (XF32) {
        const float* xp = (const float*)X + (size_t)arow * KD;
        #pragma unroll
        for (int kt = 0; kt < KT; ++kt) {
          const float4* p = (const float4*)(xp + kt * 32 + quad * 8);
          float4 a = p[0], b = p[1];
          s16x8 fr;
          fr[0] = f2bfs(a.x); fr[1] = f2bfs(a.y); fr[2] = f2bfs(a.z); fr[3] = f2bfs(a.w);
          fr[4] = f2bfs(b.x); fr[5] = f2bfs(b.y); fr[6] = f2bfs(b.z); fr[7] = f2bfs(b.w);
          afrag[t][kt] = fr;
        }
      } else {
        const short* xp = (const short*)X + (size_t)arow * KD;
        #pragma unroll
        for (int kt = 0; kt < KT; ++kt)
          afrag[t][kt] = *(const s16x8*)(xp + kt * 32 + quad * 8);
      }
    } else {
      #pragma unroll
      for (int kt = 0; kt < KT; ++kt)
        afrag[t][kt] = (s16x8){0,0,0,0,0,0,0,0};
    }
  }

  const short* wts[4] = {WTq, WTk, WTv, WTs};
  const float* bias[4] = {bq, bk, bv, bs};

  #pragma unroll
  for (int mat = 0; mat < 4; ++mat) {
    if (mat > 0) __syncthreads();
    {
      const uint4* src = (const uint4*)wts[mat];
      uint4* dst = (uint4*)lds;
      #pragma unroll
      for (int i = 0; i < CHUNKS / 256; ++i)
        dst[tid + i * 256] = src[tid + i * 256];
    }
    __syncthreads();

    f32x4 acc[4][2];
    #pragma unroll
    for (int c4 = 0; c4 < 4; ++c4) {
      float b = bias[mat][ch * 64 + c4 * 16 + mm];
      f32x4 av = {b, b, b, b};
      acc[c4][0] = av; acc[c4][1] = av;
    }
    #pragma unroll
    for (int kt = 0; kt < KT; ++kt) {
      #pragma unroll
      for (int c4 = 0; c4 < 4; ++c4) {
        s16x8 bfrag = *(const s16x8*)(lds + ((((kt * 4 + quad) << 7) + ch * 64 + c4 * 16 + mm) << 3));
        acc[c4][0] = __builtin_amdgcn_mfma_f32_16x16x32_bf16(afrag[0][kt], bfrag, acc[c4][0], 0, 0, 0);
        acc[c4][1] = __builtin_amdgcn_mfma_f32_16x16x32_bf16(afrag[1][kt], bfrag, acc[c4][1], 0, 0, 0);
      }
    }
    if (mat == 1 || mat == 2) {
      const int voff = (mat == 2) ? 8 : 0;
      #pragma unroll
      for (int c4 = 0; c4 < 4; ++c4) {
        const int col = ch * 64 + c4 * 16 + mm;
        const int bpos = ((col >> 3) << 4) + voff + (col & 7);  // interleaved KV byte
        #pragma unroll
        for (int t = 0; t < 2; ++t) {
          #pragma unroll
          for (int r = 0; r < 4; ++r) {
            int row = rowbase + t * 16 + quad * 4 + r;
            if (row < N_NODES)
              KV8[(size_t)row * 256 + bpos] = f2fp8(acc[c4][t][r]);
          }
        }
      }
    } else {
      short* O = (mat == 0) ? Qo : So;
      #pragma unroll
      for (int c4 = 0; c4 < 4; ++c4) {
        const int col = ch * 64 + c4 * 16 + mm;
        #pragma unroll
        for (int t = 0; t < 2; ++t) {
          #pragma unroll
          for (int r = 0; r < 4; ++r) {
            int row = rowbase + t * 16 + quad * 4 + r;
            if (row < N_NODES)
              ((__hip_bfloat16*)O)[(size_t)row * 128 + col] = __float2bfloat16(acc[c4][t][r]);
          }
        }
      }
    }
  }
}

// ---------------- C1/C2: scan ----------------
__global__ __launch_bounds__(256)
void scan1(const int* __restrict__ cnt, int* __restrict__ offs, int* __restrict__ bsum) {
  __shared__ int wsum[4];
  int t = threadIdx.x, lane = t & 63, w = t >> 6;
  int i = blockIdx.x * 256 + t;
  int v = (i < N_NODES) ? cnt[i] : 0;
  int x = v;
  #pragma unroll
  for (int o = 1; o < 64; o <<= 1) { int y = __shfl_up(x, o, 64); if (lane >= o) x += y; }
  if (lane == 63) wsum[w] = x;
  __syncthreads();
  if (t == 0) {
    int run = 0;
    #pragma unroll
    for (int k = 0; k < 4; ++k) { int tv = wsum[k]; wsum[k] = run; run += tv; }
    bsum[blockIdx.x] = run;
  }
  __syncthreads();
  if (i <= N_NODES) offs[i] = wsum[w] + x - v;   // block-local exclusive prefix
}

__global__ __launch_bounds__(256)
void scan2(int* __restrict__ bsum) {
  __shared__ int wsum[4];
  int t = threadIdx.x, lane = t & 63, w = t >> 6;
  int v = (t < NB_SCAN) ? bsum[t] : 0;
  int x = v;
  #pragma unroll
  for (int o = 1; o < 64; o <<= 1) { int y = __shfl_up(x, o, 64); if (lane >= o) x += y; }
  if (lane == 63) wsum[w] = x;
  __syncthreads();
  if (t == 0) {
    int run = 0;
    #pragma unroll
    for (int k = 0; k < 4; ++k) { int tv = wsum[k]; wsum[k] = run; run += tv; }
  }
  __syncthreads();
  if (t < NB_SCAN) bsum[t] = wsum[w] + x - v;    // exclusive prefix of block sums
}

// ---------------- D: layer-1 gemm + atomic-free edge scatter fused (R1 form) ----------------
__global__ __launch_bounds__(256)
void scatter_gemm1(const int* __restrict__ ei, const int* __restrict__ offs,
                   const int* __restrict__ bsum, const unsigned short* __restrict__ rank,
                   int* __restrict__ ssrc,
                   const float* __restrict__ X,
                   const short* __restrict__ w1q, const short* __restrict__ w1k,
                   const short* __restrict__ w1v, const short* __restrict__ w1s,
                   const float* __restrict__ b1q, const float* __restrict__ b1k,
                   const float* __restrict__ b1v, const float* __restrict__ b1s,
                   short* Qb, unsigned char* KV8, short* Sb)
{
  __shared__ short lds[IN_CH * 128];   // 16 KB
  int bx = blockIdx.x;
  if (bx >= NB_GEMM) {
    int e0 = (bx - NB_GEMM) * 1024 + threadIdx.x * 4;
    if (e0 >= N_EDGES) return;
    if (e0 + 3 < N_EDGES) {
      int4 sv = *(const int4*)(ei + e0);
      int4 dv = *(const int4*)(ei + N_EDGES + e0);
      ushort4 rv = *(const ushort4*)(rank + e0);
      int d0 = clamp_id(dv.x), d1 = clamp_id(dv.y);
      int d2 = clamp_id(dv.z), d3 = clamp_id(dv.w);
      int p0 = offs[d0] + bsum[d0 >> 8] + rv.x;
      int p1 = offs[d1] + bsum[d1 >> 8] + rv.y;
      int p2 = offs[d2] + bsum[d2 >> 8] + rv.z;
      int p3 = offs[d3] + bsum[d3 >> 8] + rv.w;
      ssrc[p0] = clamp_id(sv.x);
      ssrc[p1] = clamp_id(sv.y);
      ssrc[p2] = clamp_id(sv.z);
      ssrc[p3] = clamp_id(sv.w);
    } else {
      for (int j = 0; j < 4; ++j) {
        int e = e0 + j;
        if (e < N_EDGES) {
          int src = clamp_id(ei[e]);
          int dst = clamp_id(ei[N_EDGES + e]);
          ssrc[offs[dst] + bsum[dst >> 8] + rank[e]] = src;
        }
      }
    }
    return;
  }
  gemm_body<IN_CH, 1>(bx, X, w1q, w1k, w1v, w1s, b1q, b1k, b1v, b1s,
                      Qb, KV8, Sb, lds);
}

// ---------------- attention (fp8 K/V, interleaved 256B rows) ----------------
// R6: 4 edge slots x 16 channel-lanes, v_pk_fma_f32 inner math (attn is VALU-bound:
// R5 VALUBusy 74%, MfmaUtil 0). R7: DPP quad-sum for the per-edge logit reduce
// + single uint4 K|V load. R7fix: kv.x/kv.y are the K pairs (bytes 0-7 of the
// lane's 16B group), kv.z/kv.w the V pairs — the failed R7 had them crossed.
// No-max softmax in exp2 domain; 1-deep K/V register prefetch.
// H may alias S (in-place per dst row: the dst's own wave reads S before writing H).
__global__ __launch_bounds__(256)
void attn_kernel(const unsigned short* __restrict__ Q, const unsigned char* __restrict__ KV8,
                 const unsigned short* S,
                 const int* __restrict__ offs, const int* __restrict__ bsum,
                 const int* __restrict__ ssrc, unsigned short* H)
{
  const int dst = blockIdx.x * 4 + (threadIdx.x >> 6);
  if (dst >= N_NODES) return;               // wave-uniform
  const int lane = threadIdx.x & 63;
  const int sub  = lane >> 4;               // edge slot 0..3
  const int cl   = lane & 15;               // 8 channels per lane

  const float qs = 0.17677669529663687f * 1.4426950408889634f;  // 1/sqrt(32)*log2(e)
  uint4 qw = *(const uint4*)(Q + (size_t)dst * 128 + cl * 8);
  f32x2 q2[4], a2[4];
  #pragma unroll
  for (int i = 0; i < 4; ++i) {
    unsigned w = ((unsigned*)&qw)[i];
    f32x2 t; t.x = bfbits2f(w & 0xffffu) * qs; t.y = bfhi2f(w) * qs;
    q2[i] = t;
    a2[i].x = 0.f; a2[i].y = 0.f;
  }
  float s = 0.f;

  const int e0 = offs[dst] + bsum[dst >> 8];
  const int e1 = offs[dst + 1] + bsum[(dst + 1) >> 8];
  const int iters = (e1 - e0 + 3) >> 2;

  if (iters > 0) {
    int e = e0 + sub;
    bool have = (e < e1);
    int src = have ? ssrc[e] : ssrc[e0];
    float ph = have ? 1.f : 0.f;
    uint4 kv = *(const uint4*)(KV8 + (size_t)src * 256 + cl * 16);

    for (int it = 0; it < iters; ++it) {
      uint4 kvn;
      int en = e + 4;
      bool haven = (en < e1);
      float phn = haven ? 1.f : 0.f;
      if (it + 1 < iters) {                 // wave-uniform
        int srcn = haven ? ssrc[en] : ssrc[e0];
        kvn = *(const uint4*)(KV8 + (size_t)srcn * 256 + cl * 16);
      } else {
        kvn = kv;
      }
      // Lane's 16B group: kv.x = K ch 0-3, kv.y = K ch 4-7, kv.z = V ch 0-3, kv.w = V ch 4-7.
      f32x2 k0 = fp8pair<false>(kv.x), k1 = fp8pair<true>(kv.x);
      f32x2 k2 = fp8pair<false>(kv.y), k3 = fp8pair<true>(kv.y);
      f32x2 zz; zz.x = 0.f; zz.y = 0.f;
      f32x2 dd = pkfma(q2[0], k0, zz);
      dd = pkfma(q2[1], k1, dd);
      dd = pkfma(q2[2], k2, dd);
      dd = pkfma(q2[3], k3, dd);
      float d = quad_sum(dd.x + dd.y);      // 4-lane head reduce on the VALU (DPP)
      float p = exp2f(d) * ph;
      s += p;
      f32x2 p2; p2.x = p; p2.y = p;
      f32x2 v0 = fp8pair<false>(kv.z), v1 = fp8pair<true>(kv.z);
      f32x2 v2 = fp8pair<false>(kv.w), v3 = fp8pair<true>(kv.w);
      a2[0] = pkfma(p2, v0, a2[0]);
      a2[1] = pkfma(p2, v1, a2[1]);
      a2[2] = pkfma(p2, v2, a2[2]);
      a2[3] = pkfma(p2, v3, a2[3]);
      kv = kvn; ph = phn; e = en;
    }
  }

  s += __shfl_xor(s, 16, 64);
  s += __shfl_xor(s, 32, 64);
  #pragma unroll
  for (int i = 0; i < 4; ++i) {
    f32x2 t;
    t.x = __shfl_xor(a2[i].x, 16, 64);
    t.y = __shfl_xor(a2[i].y, 16, 64);
    a2[i] = pkadd(a2[i], t);
    t.x = __shfl_xor(a2[i].x, 32, 64);
    t.y = __shfl_xor(a2[i].y, 32, 64);
    a2[i] = pkadd(a2[i], t);
  }
  const float inv = (s > 0.f) ? (1.0f / s) : 0.f;

  if (sub == 0) {
    uint4 sw = *(const uint4*)(S + (size_t)dst * 128 + cl * 8);
    uint4 ow;
    #pragma unroll
    for (int i = 0; i < 4; ++i) {
      unsigned w = ((unsigned*)&sw)[i];
      float o0 = fmaxf(a2[i].x * inv + bfbits2f(w & 0xffffu), 0.f);
      float o1 = fmaxf(a2[i].y * inv + bfhi2f(w), 0.f);
      ((unsigned*)&ow)[i] = (unsigned)f2bfu(o0) | ((unsigned)f2bfu(o1) << 16);
    }
    *(uint4*)(H + (size_t)dst * 128 + cl * 8) = ow;
  }
}

// ---------------- F: layer-2 gemm ----------------
__global__ __launch_bounds__(256)
void gemm2(const short* __restrict__ X,
           const short* __restrict__ w2q, const short* __restrict__ w2k,
           const short* __restrict__ w2v, const short* __restrict__ w2s,
           const float* __restrict__ b2q, const float* __restrict__ b2k,
           const float* __restrict__ b2v, const float* __restrict__ b2s,
           short* Qb, unsigned char* KV8, short* Sb)
{
  __shared__ short lds[HID_CH * 128];  // 32 KB
  gemm_body<HID_CH, 0>(blockIdx.x, X, w2q, w2k, w2v, w2s, b2q, b2k, b2v, b2s,
                       Qb, KV8, Sb, lds);
}

// ---------------- pooling (16 partials/graph, few atomics) ----------------
__device__ __forceinline__ int lower_bound_i(const int* __restrict__ b, int n, int val) {
  int lo = 0, hi = n;
  while (lo < hi) { int mid = (lo + hi) >> 1; if (b[mid] < val) lo = mid + 1; else hi = mid; }
  return lo;
}

__global__ __launch_bounds__(128)
void pool_partial(const __hip_bfloat16* __restrict__ H, const int* __restrict__ batch,
                  float* __restrict__ pooled)
{
  const int g = blockIdx.x >> 4, p = blockIdx.x & 15, t = threadIdx.x;
  const int s = lower_bound_i(batch, N_NODES, g);
  const int e = lower_bound_i(batch, N_NODES, g + 1);
  const int len = e - s;
  if (len <= 0) return;
  const int chunk = (len + 15) >> 4;
  const int a = s + p * chunk;
  const int b = min(a + chunk, e);
  if (a >= b) return;
  float sum = 0.f;
  for (int i = a; i < b; ++i) sum += bf2f(H[(size_t)i * 128 + t]);
  atomicAdd(&pooled[g * 128 + t], sum);
}

__global__ __launch_bounds__(128)
void pool_final(const float* __restrict__ pooled, const int* __restrict__ batch,
                const float* __restrict__ Wl, const float* __restrict__ bl,
                float* __restrict__ out)
{
  const int g = blockIdx.x, t = threadIdx.x;
  __shared__ float r0[128], r1[128];
  const int s = lower_bound_i(batch, N_NODES, g);
  const int e = lower_bound_i(batch, N_NODES, g + 1);
  const float inv = 1.0f / (float)max(e - s, 1);
  const float pc = pooled[g * 128 + t] * inv;
  r0[t] = pc * Wl[t * 2 + 0];
  r1[t] = pc * Wl[t * 2 + 1];
  __syncthreads();
  for (int o = 64; o > 0; o >>= 1) {
    if (t < o) { r0[t] += r0[t + o]; r1[t] += r1[t + o]; }
    __syncthreads();
  }
  if (t == 0) {
    out[g * 2 + 0] = r0[0] + bl[0];
    out[g * 2 + 1] = r1[0] + bl[1];
  }
}

// ---------------- launch ----------------

extern "C" void kernel_launch(void* const* d_in, const int* in_sizes, int n_in,
                              void* d_out, int out_size, void* d_ws, size_t ws_size,
                              hipStream_t stream) {
  uintptr_t base = (uintptr_t)d_ws;
  auto take = [&](size_t bytes) -> uintptr_t {
    uintptr_t p = base;
    base += (bytes + 255) & ~(size_t)255;
    return p;
  };

  // cnt + pooled first and contiguous: zeroed by ONE hipMemsetAsync.
  int*   cnt    = (int*)take((size_t)N_NODES * 4);
  float* pooled = (float*)take((size_t)N_GRAPHS * 128 * 4);
  int*   offs   = (int*)take((size_t)(N_NODES + 1) * 4);
  int*   bsum   = (int*)take((size_t)NB_SCAN * 4);
  int*   ssrc   = (int*)take((size_t)N_EDGES * 4);
  unsigned short* rank = (unsigned short*)take((size_t)N_EDGES * 2);
  short* Qb     = (short*)take((size_t)N_NODES * 128 * 2);
  unsigned char* KV8 = (unsigned char*)take((size_t)N_NODES * 256);  // fp8 interleaved K|V rows
  short* Sb     = (short*)take((size_t)N_NODES * 128 * 2);  // S / H / layer-2 X (in-place)
  short* wt1q   = (short*)take((size_t)IN_CH * 128 * 2);
  short* wt1k   = (short*)take((size_t)IN_CH * 128 * 2);
  short* wt1v   = (short*)take((size_t)IN_CH * 128 * 2);
  short* wt1s   = (short*)take((size_t)IN_CH * 128 * 2);
  short* wt2q   = (short*)take((size_t)HID_CH * 128 * 2);
  short* wt2k   = (short*)take((size_t)HID_CH * 128 * 2);
  short* wt2v   = (short*)take((size_t)HID_CH * 128 * 2);
  short* wt2s   = (short*)take((size_t)HID_CH * 128 * 2);

  const int* ei    = (const int*)d_in[1];   // int32 per harness contract
  const int* batch = (const int*)d_in[2];   // int32 per harness contract

  // Zero cnt..pooled span (contiguous, one DMA memset; graph-capturable).
  size_t zspan = (size_t)((char*)pooled + (size_t)N_GRAPHS * 128 * 4 - (char*)cnt);
  hipMemsetAsync(cnt, 0, zspan, stream);

  // A: degree count + rank capture (blocks first) + weight canonicalization
  prep<<<NB_CNT4 + NB_CONV, 256, 0, stream>>>(
      ei, cnt, rank,
      (const float*)d_in[3], (const float*)d_in[5], (const float*)d_in[7], (const float*)d_in[9],
      (const float*)d_in[11], (const float*)d_in[13], (const float*)d_in[15], (const float*)d_in[17],
      (__hip_bfloat16*)wt1q, (__hip_bfloat16*)wt1k, (__hip_bfloat16*)wt1v, (__hip_bfloat16*)wt1s,
      (__hip_bfloat16*)wt2q, (__hip_bfloat16*)wt2k, (__hip_bfloat16*)wt2v, (__hip_bfloat16*)wt2s);

  // C: scan
  scan1<<<NB_SCAN, 256, 0, stream>>>(cnt, offs, bsum);
  scan2<<<1, 256, 0, stream>>>(bsum);

  // D: layer-1 QKVS gemm (blocks first) + atomic-free edge scatter (backfill)
  scatter_gemm1<<<NB_GEMM + NB_CNT4, 256, 0, stream>>>(
      ei, offs, bsum, rank, ssrc,
      (const float*)d_in[0],
      wt1q, wt1k, wt1v, wt1s,
      (const float*)d_in[4], (const float*)d_in[6], (const float*)d_in[8], (const float*)d_in[10],
      Qb, KV8, Sb);

  const int attn_grid = (N_NODES + 3) / 4;

  // E: layer-1 attention (writes H in place into Sb)
  attn_kernel<<<attn_grid, 256, 0, stream>>>(
      (const unsigned short*)Qb, KV8,
      (const unsigned short*)Sb, offs, bsum, ssrc, (unsigned short*)Sb);

  // F: layer-2 gemm (X = Sb, S in-place)
  gemm2<<<NB_GEMM, 256, 0, stream>>>(
      Sb, wt2q, wt2k, wt2v, wt2s,
      (const float*)d_in[12], (const float*)d_in[14], (const float*)d_in[16], (const float*)d_in[18],
      Qb, KV8, Sb);

  // G: layer-2 attention (writes H in place into Sb)
  attn_kernel<<<attn_grid, 256, 0, stream>>>(
      (const unsigned short*)Qb, KV8,
      (const unsigned short*)Sb, offs, bsum, ssrc, (unsigned short*)Sb);

  // Pool: 16 partials/graph -> one atomic per channel per partial, then final linear
  pool_partial<<<N_GRAPHS * 16, 128, 0, stream>>>(
      (const __hip_bfloat16*)Sb, batch, pooled);
  pool_final<<<N_GRAPHS, 128, 0, stream>>>(pooled, batch, (const float*)d_in[19],
                                           (const float*)d_in[20], (float*)d_out);
}